// Round 10
// baseline (1339.149 us; speedup 1.0000x reference)
//
#include <hip/hip_runtime.h>
#include <math.h>

#define DD 256
#define NQQ 900
#define NBS 4
#define NLAYER 6
#define BEVH 200
#define BEVW 200
#define ROWS (NBS*NQQ)   // 3600
#define BIGN (1<<30)
#define KDEF 2080        // deform fused K: 2048 + 8 sacc + 24 zero

typedef __attribute__((ext_vector_type(8))) short bf16x8;
typedef __attribute__((ext_vector_type(4))) float f32x4;

__device__ __forceinline__ float sigmoidf_(float x){ return 1.0f/(1.0f+expf(-x)); }
__device__ __forceinline__ float invsigf_(float x){
  x = fminf(fmaxf(x,0.0f),1.0f);
  float lo = fmaxf(x,1e-5f), hi = fmaxf(1.0f-x,1e-5f);
  return logf(lo/hi);
}
__device__ __forceinline__ unsigned f2bf1(float x){
  unsigned u = __float_as_uint(x);
  return (u + 0x7fffu + ((u>>16)&1u)) >> 16;
}
__device__ __forceinline__ unsigned pk2(float a, float b){
  return f2bf1(a) | (f2bf1(b)<<16);
}
__device__ __forceinline__ float bf2f(unsigned u){ return __uint_as_float(u<<16); }
__device__ __forceinline__ ushort4 pk4(float4 y){
  ushort4 o; o.x=(ushort)f2bf1(y.x); o.y=(ushort)f2bf1(y.y);
  o.z=(ushort)f2bf1(y.z); o.w=(ushort)f2bf1(y.w); return o;
}

// ---------------------------------------------------------------------------
// fp32 GEMM (ref head only).
// ---------------------------------------------------------------------------
__global__ __launch_bounds__(256) void gemm_k(
    const float* __restrict__ A, int lda,
    const float* __restrict__ W, const float* __restrict__ B,
    float* __restrict__ Y, int M, int N, int K, int ldy, int act)
{
  __shared__ float As[2][32][66];
  __shared__ float Ws[2][32][66];
  const int t = threadIdx.x;
  const int m0 = blockIdx.x*64, n0 = blockIdx.y*64;
  const int lr = t >> 2, kq = (t & 3) << 3;
  const int tx = t & 15, ty = t >> 4;
  const bool aok = (m0 + lr) < M;
  const bool wok = (n0 + lr) < N;
  const float* ap  = A + (size_t)(m0+lr)*lda + kq;
  const float* wp  = W + (size_t)(n0+lr)*K + kq;
  float4 pa[2], pw[2];
  auto loadch = [&](int kc) {
    #pragma unroll
    for (int i=0;i<2;++i) {
      pa[i] = aok ? *(const float4*)(ap + kc + i*4) : make_float4(0,0,0,0);
      pw[i] = wok ? *(const float4*)(wp + kc + i*4) : make_float4(0,0,0,0);
    }
  };
  auto storech = [&](int bf) {
    #pragma unroll
    for (int i=0;i<2;++i) {
      const int kk = kq + i*4;
      As[bf][kk+0][lr]=pa[i].x; As[bf][kk+1][lr]=pa[i].y;
      As[bf][kk+2][lr]=pa[i].z; As[bf][kk+3][lr]=pa[i].w;
      Ws[bf][kk+0][lr]=pw[i].x; Ws[bf][kk+1][lr]=pw[i].y;
      Ws[bf][kk+2][lr]=pw[i].z; Ws[bf][kk+3][lr]=pw[i].w;
    }
  };
  float acc[4][4] = {};
  loadch(0); storech(0); __syncthreads();
  const int NC = K >> 5;
  for (int c=0; c<NC; ++c) {
    if (c+1 < NC) loadch((c+1) << 5);
    const int bf = c & 1;
    #pragma unroll
    for (int k=0;k<32;++k) {
      const float4 a4 = *(const float4*)&As[bf][k][ty<<2];
      const float4 w4 = *(const float4*)&Ws[bf][k][tx<<2];
      const float av[4] = {a4.x,a4.y,a4.z,a4.w};
      const float wv[4] = {w4.x,w4.y,w4.z,w4.w};
      #pragma unroll
      for (int r=0;r<4;++r)
        #pragma unroll
        for (int cc=0;cc<4;++cc) acc[r][cc] += av[r]*wv[cc];
    }
    if (c+1 < NC) { storech((c+1)&1); __syncthreads(); }
  }
  const int gn0 = n0 + (tx<<2);
  #pragma unroll
  for (int r=0;r<4;++r) {
    const int gm = m0 + (ty<<2) + r;
    if (gm >= M) continue;
    for (int cc=0; cc<4 && gn0+cc<N; ++cc) {
      float x = acc[r][cc] + (B ? B[gn0+cc] : 0.0f);
      if (act==1) x = fmaxf(x,0.0f);
      else if (act==2) x = sigmoidf_(x);
      Y[(size_t)gm*ldy + gn0+cc] = x;
    }
  }
}

// ---------------------------------------------------------------------------
// bf16 MFMA GEMM v3: templated BM (64 or 32), BN=64. Dual-A/W/bias/Y.
// ---------------------------------------------------------------------------
template<int BM>
__global__ __launch_bounds__(256) void gemmb_k(
    const ushort* __restrict__ A0, const ushort* __restrict__ A1, int NA, int lda,
    const ushort* __restrict__ W0, const ushort* __restrict__ W1, int NW,
    const float* __restrict__ B0, const float* __restrict__ B1, int NB,
    void* __restrict__ Y0, int ldy0, int obf0,
    void* __restrict__ Y1, int ldy1, int obf1, int NY,
    int M, int N, int K, int reluN)
{
  __shared__ ushort As[2][BM*32];
  __shared__ ushort Bs[2][2048];
  const int t = threadIdx.x;
  const int m0 = blockIdx.x*BM, n0 = blockIdx.y*64;
  const ushort* A = (n0 < NA) ? A0 : A1;
  const int srow = t>>2, scb = t&3;
  const int wrow = n0 + srow;
  const bool wok = wrow < N;
  const ushort* wp = (wrow < NW) ? (W0 + (size_t)wrow*K + scb*8)
                                 : (W1 + (size_t)(wrow-NW)*K + scb*8);
  bool aok; const ushort* ap;
  if constexpr (BM==64) { aok = (m0+srow)<M; }
  else { aok = (t<128) && (m0+srow)<M; }
  ap = A + (size_t)(m0 + (aok?srow:0))*lda + scb*8;
  const int sidx = srow*32 + ((scb ^ (srow&3))<<3);
  const bf16x8 zf = {0,0,0,0,0,0,0,0};

  bf16x8 pa, pw;
  auto loadg = [&](int kc){
    pa = aok ? *(const bf16x8*)(ap+kc) : zf;
    pw = wok ? *(const bf16x8*)(wp+kc) : zf;
  };
  auto writes = [&](int bf){
    if (BM==64 || t<128) *(bf16x8*)&As[bf][sidx] = pa;
    *(bf16x8*)&Bs[bf][sidx] = pw;
  };

  const int wv = t>>6, lane = t&63;
  const int fm = lane&15, kb = lane>>4;

  auto writeout = [&](float x, int row, int col){
    if (row >= M || col >= N) return;
    if (col < reluN) x = fmaxf(x, 0.0f);
    if (col < NY) {
      if (obf0) ((ushort*)Y0)[(size_t)row*ldy0 + col] = (ushort)f2bf1(x);
      else      ((float*)Y0)[(size_t)row*ldy0 + col] = x;
    } else {
      const int c2 = col - NY;
      if (obf1) ((ushort*)Y1)[(size_t)row*ldy1 + c2] = (ushort)f2bf1(x);
      else      ((float*)Y1)[(size_t)row*ldy1 + c2] = x;
    }
  };

  const int NS = K>>5;
  if constexpr (BM==64) {
    const int wr = wv>>1, wc = wv&1;
    const int arow0 = wr*32 + fm, arow1 = arow0 + 16;
    const int bcol0 = wc*32 + fm, bcol1 = bcol0 + 16;
    const int ai0 = arow0*32 + ((kb^(arow0&3))<<3);
    const int ai1 = arow1*32 + ((kb^(arow1&3))<<3);
    const int bi0 = bcol0*32 + ((kb^(bcol0&3))<<3);
    const int bi1 = bcol1*32 + ((kb^(bcol1&3))<<3);
    f32x4 acc00={0,0,0,0}, acc01={0,0,0,0}, acc10={0,0,0,0}, acc11={0,0,0,0};
    loadg(0); writes(0); __syncthreads();
    for (int s=0; s<NS; ++s) {
      if (s+1<NS) loadg((s+1)<<5);
      const int bf = s&1;
      bf16x8 a0 = *(bf16x8*)&As[bf][ai0];
      bf16x8 a1 = *(bf16x8*)&As[bf][ai1];
      bf16x8 b0 = *(bf16x8*)&Bs[bf][bi0];
      bf16x8 b1 = *(bf16x8*)&Bs[bf][bi1];
      acc00 = __builtin_amdgcn_mfma_f32_16x16x32_bf16(a0,b0,acc00,0,0,0);
      acc01 = __builtin_amdgcn_mfma_f32_16x16x32_bf16(a0,b1,acc01,0,0,0);
      acc10 = __builtin_amdgcn_mfma_f32_16x16x32_bf16(a1,b0,acc10,0,0,0);
      acc11 = __builtin_amdgcn_mfma_f32_16x16x32_bf16(a1,b1,acc11,0,0,0);
      if (s+1<NS) { __syncthreads(); writes((s+1)&1); __syncthreads(); }
    }
    #pragma unroll
    for (int fr=0; fr<2; ++fr)
      #pragma unroll
      for (int fc=0; fc<2; ++fc) {
        const f32x4 av = fr ? (fc ? acc11 : acc10) : (fc ? acc01 : acc00);
        const int col = n0 + wc*32 + fc*16 + fm;
        const float bias = (col<N) ? ((col<NB) ? B0[col] : B1[col-NB]) : 0.0f;
        #pragma unroll
        for (int r=0; r<4; ++r)
          writeout(av[r] + bias, m0 + wr*32 + fr*16 + kb*4 + r, col);
      }
  } else {
    const int ai0 = fm*32 + ((kb^(fm&3))<<3);
    const int ai1 = (fm+16)*32 + ((kb^(fm&3))<<3);
    const int bcol = wv*16 + fm;
    const int bi = bcol*32 + ((kb^(bcol&3))<<3);
    f32x4 acc0={0,0,0,0}, acc1={0,0,0,0};
    loadg(0); writes(0); __syncthreads();
    for (int s=0; s<NS; ++s) {
      if (s+1<NS) loadg((s+1)<<5);
      const int bf = s&1;
      bf16x8 a0 = *(bf16x8*)&As[bf][ai0];
      bf16x8 a1 = *(bf16x8*)&As[bf][ai1];
      bf16x8 b  = *(bf16x8*)&Bs[bf][bi];
      acc0 = __builtin_amdgcn_mfma_f32_16x16x32_bf16(a0,b,acc0,0,0,0);
      acc1 = __builtin_amdgcn_mfma_f32_16x16x32_bf16(a1,b,acc1,0,0,0);
      if (s+1<NS) { __syncthreads(); writes((s+1)&1); __syncthreads(); }
    }
    const int col = n0 + wv*16 + fm;
    const float bias = (col<N) ? ((col<NB) ? B0[col] : B1[col-NB]) : 0.0f;
    #pragma unroll
    for (int r=0; r<4; ++r) {
      writeout(acc0[r] + bias, m0 + kb*4 + r, col);
      writeout(acc1[r] + bias, m0 + 16 + kb*4 + r, col);
    }
  }
}

// ---------------------------------------------------------------------------
// Fused tail: reg1|cls1 + clsLN1 + reg2|cls2 + clsLN2 + reg3/cls3 + refout.
// All per-row. 225 blocks x 16 rows, 256 threads (4 waves). Weights streamed
// from L2 into a 64x128 LDS chunk; intermediates live in LDS.
// ---------------------------------------------------------------------------
__global__ __launch_bounds__(256) void tail_k(
    const ushort* __restrict__ qb,
    const ushort* __restrict__ w1, const float* __restrict__ b1,
    const float* __restrict__ ln1w, const float* __restrict__ ln1b,
    const ushort* __restrict__ w2r, const ushort* __restrict__ w2c,
    const float* __restrict__ b2r, const float* __restrict__ b2c,
    const float* __restrict__ ln2w, const float* __restrict__ ln2b,
    const float* __restrict__ rw3, const float* __restrict__ rb3,
    const float* __restrict__ cw3, const float* __restrict__ cb3,
    float* __restrict__ ref, float* __restrict__ outL)
{
  __shared__ ushort As_[16*264];   // A tile (qb rows); later reg2-out bf16 [row*264+col]
  __shared__ ushort Ws_[64*128];   // W chunk
  __shared__ ushort Ar_[16*256];   // relu(reg1) bf16, swizzled A-layout
  __shared__ ushort Ac_[16*256];   // relu(LN(cls1)) bf16, swizzled A-layout
  __shared__ float  Hc_[16*264];   // cls1 raw f32; later cls2 raw f32

  const int t = threadIdx.x;
  const int m0 = blockIdx.x*16;
  const int wv = t>>6, lane = t&63;
  const int fm = lane&15, kb = lane>>4;
  const int colL = wv*16 + fm;

  // P0: load A rows
  {
    const int row = t>>4, seg = t&15;
    const ushort* ap = qb + (size_t)(m0+row)*256 + seg*16;
    #pragma unroll
    for (int j=0;j<2;++j) {
      bf16x8 v = *(const bf16x8*)(ap + j*8);
      const int k = seg*16 + j*8;
      *(bf16x8*)&As_[row*264 + ((k>>5)<<5) + ((((k>>3)&3)^(row&3))<<3)] = v;
    }
  }
  __syncthreads();

  // GEMM1: out512 = qb16 @ w1^T + b1 ; reg half relu->Ar, cls half f32->Hc
  for (int chunk=0; chunk<8; ++chunk) {
    f32x4 acc = {0,0,0,0};
    for (int kc=0; kc<2; ++kc) {
      __syncthreads();
      for (int i=t; i<1024; i+=256) {
        const int r = i>>4, kl = (i&15)*8;
        bf16x8 v = *(const bf16x8*)(w1 + (size_t)(chunk*64+r)*256 + kc*128 + kl);
        *(bf16x8*)&Ws_[r*128 + ((kl>>5)<<5) + ((((kl>>3)&3)^(r&3))<<3)] = v;
      }
      __syncthreads();
      #pragma unroll
      for (int s=0;s<4;++s) {
        const int st = kc*4 + s;
        bf16x8 af  = *(bf16x8*)&As_[fm*264 + (st<<5) + ((kb^(fm&3))<<3)];
        bf16x8 bfv = *(bf16x8*)&Ws_[colL*128 + (s<<5) + ((kb^(colL&3))<<3)];
        acc = __builtin_amdgcn_mfma_f32_16x16x32_bf16(af, bfv, acc, 0,0,0);
      }
    }
    const int gcol = chunk*64 + colL;
    const float bias = b1[gcol];
    #pragma unroll
    for (int r=0;r<4;++r) {
      const int row = kb*4 + r;
      float v = acc[r] + bias;
      if (chunk < 4) {
        v = fmaxf(v, 0.0f);
        Ar_[row*256 + ((gcol>>5)<<5) + ((((gcol>>3)&3)^(row&3))<<3) + (gcol&7)] = (ushort)f2bf1(v);
      } else {
        Hc_[row*264 + (gcol-256)] = v;
      }
    }
  }
  __syncthreads();

  // LN1 on cls1 (Hc) -> relu -> Ac (bf16 swizzled)
  {
    const int row = t>>4, cg = t&15;
    float x[16]; float s1=0.f, s2=0.f;
    #pragma unroll
    for (int j=0;j<16;j+=4) {
      float4 e = *(float4*)&Hc_[row*264 + cg*16 + j];
      x[j]=e.x; x[j+1]=e.y; x[j+2]=e.z; x[j+3]=e.w;
      s1 += e.x+e.y+e.z+e.w;
      s2 += e.x*e.x+e.y*e.y+e.z*e.z+e.w*e.w;
    }
    s1 += __shfl_xor(s1,1); s1 += __shfl_xor(s1,2); s1 += __shfl_xor(s1,4); s1 += __shfl_xor(s1,8);
    s2 += __shfl_xor(s2,1); s2 += __shfl_xor(s2,2); s2 += __shfl_xor(s2,4); s2 += __shfl_xor(s2,8);
    const float mean = s1*(1.0f/256.0f);
    const float var  = s2*(1.0f/256.0f) - mean*mean;
    const float rs   = rsqrtf(var + 1e-5f);
    #pragma unroll
    for (int jj=0;jj<2;++jj) {
      const int k0 = cg*16 + jj*8;
      union { bf16x8 v; unsigned u[4]; } uu;
      #pragma unroll
      for (int p=0;p<4;++p) {
        const int j = jj*8 + p*2;
        const float w0 = ln1w[k0 + p*2],     b0 = ln1b[k0 + p*2];
        const float w1v = ln1w[k0 + p*2 + 1], b1v = ln1b[k0 + p*2 + 1];
        const float y0 = fmaxf((x[j]-mean)*rs*w0 + b0, 0.0f);
        const float y1 = fmaxf((x[j+1]-mean)*rs*w1v + b1v, 0.0f);
        uu.u[p] = pk2(y0, y1);
      }
      *(bf16x8*)&Ac_[row*256 + ((k0>>5)<<5) + ((((k0>>3)&3)^(row&3))<<3)] = uu.v;
    }
  }
  __syncthreads();

  // GEMM2: reg2 = relu(Ar@w2r^T+b2r) -> As_ bf16 plain; cls2 = Ac@w2c^T+b2c -> Hc f32
  for (int chunk=0; chunk<8; ++chunk) {
    const ushort* Wsrc = (chunk<4) ? w2r : w2c;
    const int wrb = (chunk&3)*64;
    f32x4 acc = {0,0,0,0};
    for (int kc=0; kc<2; ++kc) {
      __syncthreads();
      for (int i=t; i<1024; i+=256) {
        const int r = i>>4, kl = (i&15)*8;
        bf16x8 v = *(const bf16x8*)(Wsrc + (size_t)(wrb+r)*256 + kc*128 + kl);
        *(bf16x8*)&Ws_[r*128 + ((kl>>5)<<5) + ((((kl>>3)&3)^(r&3))<<3)] = v;
      }
      __syncthreads();
      #pragma unroll
      for (int s=0;s<4;++s) {
        const int st = kc*4 + s;
        const ushort* Asrc = (chunk<4) ? Ar_ : Ac_;
        bf16x8 af  = *(bf16x8*)&Asrc[fm*256 + (st<<5) + ((kb^(fm&3))<<3)];
        bf16x8 bfv = *(bf16x8*)&Ws_[colL*128 + (s<<5) + ((kb^(colL&3))<<3)];
        acc = __builtin_amdgcn_mfma_f32_16x16x32_bf16(af, bfv, acc, 0,0,0);
      }
    }
    const int gcol2 = wrb + colL;
    const float bias = (chunk<4) ? b2r[gcol2] : b2c[gcol2];
    #pragma unroll
    for (int r=0;r<4;++r) {
      const int row = kb*4 + r;
      float v = acc[r] + bias;
      if (chunk < 4) {
        v = fmaxf(v, 0.0f);
        As_[row*264 + gcol2] = (ushort)f2bf1(v);
      } else {
        Hc_[row*264 + gcol2] = v;
      }
    }
  }
  __syncthreads();

  // Final: clsLN2+relu, reg3/cls3 (weights from global, L1-resident), refout.
  {
    const int row = t>>4, sub = t&15;
    const int g = sub>>3, sl = sub&7;
    const int R = m0 + row;
    float x[32];
    if (g == 0) {
      #pragma unroll
      for (int j=0;j<32;j+=4) {
        ushort4 u = *(ushort4*)&As_[row*264 + sl*32 + j];
        x[j]=bf2f(u.x); x[j+1]=bf2f(u.y); x[j+2]=bf2f(u.z); x[j+3]=bf2f(u.w);
      }
    } else {
      float s1=0.f, s2=0.f;
      #pragma unroll
      for (int j=0;j<32;j+=4) {
        float4 e = *(float4*)&Hc_[row*264 + sl*32 + j];
        x[j]=e.x; x[j+1]=e.y; x[j+2]=e.z; x[j+3]=e.w;
        s1 += e.x+e.y+e.z+e.w;
        s2 += e.x*e.x+e.y*e.y+e.z*e.z+e.w*e.w;
      }
      s1 += __shfl_xor(s1,1); s1 += __shfl_xor(s1,2); s1 += __shfl_xor(s1,4);
      s2 += __shfl_xor(s2,1); s2 += __shfl_xor(s2,2); s2 += __shfl_xor(s2,4);
      const float mean = s1*(1.0f/256.0f);
      const float var  = s2*(1.0f/256.0f) - mean*mean;
      const float rs   = rsqrtf(var + 1e-5f);
      #pragma unroll
      for (int j=0;j<32;++j) {
        const int k = sl*32 + j;
        x[j] = fmaxf((x[j]-mean)*rs*ln2w[k] + ln2b[k], 0.0f);
      }
    }
    const float* W3 = g ? cw3 : rw3;
    float acc[10] = {};
    #pragma unroll
    for (int o=0;o<10;++o) {
      const float* wp = W3 + o*256 + sl*32;
      #pragma unroll
      for (int j=0;j<32;j+=4) {
        const float4 w = *(const float4*)(wp + j);
        acc[o] += x[j]*w.x + x[j+1]*w.y + x[j+2]*w.z + x[j+3]*w.w;
      }
    }
    #pragma unroll
    for (int o=0;o<10;++o) {
      acc[o] += __shfl_xor(acc[o],1);
      acc[o] += __shfl_xor(acc[o],2);
      acc[o] += __shfl_xor(acc[o],4);
    }
    if (sl == 0) {
      if (g) {
        float* oc = outL + (size_t)R*20;
        #pragma unroll
        for (int o=0;o<10;++o) oc[o] = acc[o] + cb3[o];
      } else {
        float tt[10];
        #pragma unroll
        for (int o=0;o<10;++o) tt[o] = acc[o] + rb3[o];
        const float rx = invsigf_(ref[R*3+0]);
        const float ry = invsigf_(ref[R*3+1]);
        const float rz = invsigf_(ref[R*3+2]);
        const float nx = sigmoidf_(tt[0]+rx);
        const float ny = sigmoidf_(tt[1]+ry);
        const float nz = sigmoidf_(tt[4]+rz);
        ref[R*3+0]=nx; ref[R*3+1]=ny; ref[R*3+2]=nz;
        float* o = outL + (size_t)R*20 + 10;
        o[0]=nx*102.4f-51.2f; o[1]=ny*102.4f-51.2f; o[2]=tt[2]; o[3]=tt[3];
        o[4]=nz*8.0f-5.0f; o[5]=tt[5]; o[6]=tt[6]; o[7]=tt[7]; o[8]=tt[8]; o[9]=tt[9];
      }
    }
  }
}

// ---------------------------------------------------------------------------
// MFMA bf16 flash attention v2: block-shared LDS K/V staging.
// ---------------------------------------------------------------------------
__global__ __launch_bounds__(256) void attn3_k(
    const ushort* __restrict__ QKb, const ushort* __restrict__ Vb, ushort* __restrict__ Ob)
{
  const int b = blockIdx.x >> 3, h = blockIdx.x & 7;
  const int wv = threadIdx.x >> 6, lane = threadIdx.x & 63;
  const int t = threadIdx.x;
  const int qt = blockIdx.y*64 + wv*16;
  const int lq = lane & 15, lg = lane >> 4;
  const int q = qt + lq;

  __shared__ ushort Ks[2][32*40];
  __shared__ ushort Vt[2][32*34];

  bf16x8 qf = *(const bf16x8*)(QKb + (size_t)(b*NQQ + min(q, NQQ-1))*512 + h*32 + lg*8);
  f32x4 ot0 = {0.f,0.f,0.f,0.f}, ot1 = {0.f,0.f,0.f,0.f};
  float m = -3e38f, l = 0.0f;

  const ushort* kg = QKb + (size_t)b*NQQ*512 + 256 + h*32;
  const ushort* vg = Vb  + (size_t)b*NQQ*256 + h*32;
  const int srow = t>>3, sc4 = (t&7)*4;

  ushort4 kv, vv;
  auto sload = [&](int k0){
    const int gr = min(k0 + srow, NQQ-1);
    kv = *(const ushort4*)(kg + (size_t)gr*512 + sc4);
    vv = *(const ushort4*)(vg + (size_t)gr*256 + sc4);
  };
  auto swrite = [&](int bf){
    *(ushort4*)&Ks[bf][srow*40 + sc4] = kv;
    Vt[bf][(sc4+0)*34 + srow] = vv.x;
    Vt[bf][(sc4+1)*34 + srow] = vv.y;
    Vt[bf][(sc4+2)*34 + srow] = vv.z;
    Vt[bf][(sc4+3)*34 + srow] = vv.w;
  };

  const int pbase = (lq + ((lg&1)<<5)) << 2;
  const bool hiC = (lg >> 1);
  const int NC = (NQQ + 31) >> 5;

  sload(0); swrite(0); __syncthreads();
  for (int c = 0; c < NC; ++c) {
    const int k0 = c<<5;
    if (c+1 < NC) sload((c+1)<<5);
    const int bf = c&1;
    bf16x8 kf0 = *(bf16x8*)&Ks[bf][lq*40 + lg*8];
    bf16x8 kf1 = *(bf16x8*)&Ks[bf][(16+lq)*40 + lg*8];
    const f32x4 z = {0.f,0.f,0.f,0.f};
    f32x4 s0 = __builtin_amdgcn_mfma_f32_16x16x32_bf16(kf0, qf, z, 0, 0, 0);
    f32x4 s1 = __builtin_amdgcn_mfma_f32_16x16x32_bf16(kf1, qf, z, 0, 0, 0);
    const float sc = 0.17677669529663687f;
    float p0[4], p1[4];
    #pragma unroll
    for (int r=0;r<4;++r) { p0[r] = s0[r]*sc; p1[r] = s1[r]*sc; }
    if (k0 + 32 > NQQ) {
      #pragma unroll
      for (int r=0;r<4;++r) {
        if (k0 + 4*lg + r      >= NQQ) p0[r] = -3e38f;
        if (k0 + 16 + 4*lg + r >= NQQ) p1[r] = -3e38f;
      }
    }
    float cm = fmaxf(fmaxf(fmaxf(p0[0],p0[1]),fmaxf(p0[2],p0[3])),
                     fmaxf(fmaxf(p1[0],p1[1]),fmaxf(p1[2],p1[3])));
    cm = fmaxf(cm, __shfl_xor(cm, 16));
    cm = fmaxf(cm, __shfl_xor(cm, 32));
    const float mn = fmaxf(m, cm);
    const float corr = __expf(m - mn);
    m = mn;
    float rs = 0.0f;
    #pragma unroll
    for (int r=0;r<4;++r) { p0[r] = __expf(p0[r]-mn); rs += p0[r]; }
    #pragma unroll
    for (int r=0;r<4;++r) { p1[r] = __expf(p1[r]-mn); rs += p1[r]; }
    rs += __shfl_xor(rs, 16);
    rs += __shfl_xor(rs, 32);
    l = l*corr + rs;
    ot0 *= corr; ot1 *= corr;

    const int c00 = (int)pk2(p0[0],p0[1]), c01 = (int)pk2(p0[2],p0[3]);
    const int c10 = (int)pk2(p1[0],p1[1]), c11 = (int)pk2(p1[2],p1[3]);
    const int A0 = __builtin_amdgcn_ds_bpermute(pbase,    c00);
    const int B0 = __builtin_amdgcn_ds_bpermute(pbase,    c10);
    const int A1 = __builtin_amdgcn_ds_bpermute(pbase,    c01);
    const int B1 = __builtin_amdgcn_ds_bpermute(pbase,    c11);
    const int A2 = __builtin_amdgcn_ds_bpermute(pbase+64, c00);
    const int B2 = __builtin_amdgcn_ds_bpermute(pbase+64, c10);
    const int A3 = __builtin_amdgcn_ds_bpermute(pbase+64, c01);
    const int B3 = __builtin_amdgcn_ds_bpermute(pbase+64, c11);
    union { bf16x8 v; int u[4]; } pv;
    pv.u[0] = hiC ? B0 : A0; pv.u[1] = hiC ? B1 : A1;
    pv.u[2] = hiC ? B2 : A2; pv.u[3] = hiC ? B3 : A3;

    bf16x8 vf0, vf1;
    {
      union { bf16x8 v; unsigned u[4]; } u0, u1;
      const int rb = 8*lg;
      #pragma unroll
      for (int jj=0;jj<4;++jj) {
        u0.u[jj] = *(const unsigned*)&Vt[bf][lq*34 + rb + 2*jj];
        u1.u[jj] = *(const unsigned*)&Vt[bf][(16+lq)*34 + rb + 2*jj];
      }
      vf0 = u0.v; vf1 = u1.v;
    }
    ot0 = __builtin_amdgcn_mfma_f32_16x16x32_bf16(vf0, pv.v, ot0, 0, 0, 0);
    ot1 = __builtin_amdgcn_mfma_f32_16x16x32_bf16(vf1, pv.v, ot1, 0, 0, 0);
    if (c+1 < NC) { __syncthreads(); swrite((c+1)&1); __syncthreads(); }
  }
  if (q < NQQ && qt < NQQ) {
    const float inv = 1.0f / l;
    ushort* op = Ob + (size_t)(b*NQQ + q)*256 + h*32;
    uint2 w0, w1;
    w0.x = pk2(ot0[0]*inv, ot0[1]*inv); w0.y = pk2(ot0[2]*inv, ot0[3]*inv);
    w1.x = pk2(ot1[0]*inv, ot1[1]*inv); w1.y = pk2(ot1[2]*inv, ot1[3]*inv);
    *(uint2*)(op + 4*lg)      = w0;
    *(uint2*)(op + 16 + 4*lg) = w1;
  }
}

// ---------------------------------------------------------------------------
// LayerNorm: optional f32 out, bf16 out, bf16(out+qpos) out.
// ---------------------------------------------------------------------------
__global__ __launch_bounds__(256) void ln_k(
    const float* X, int xld, const float* R,
    const float* __restrict__ w, const float* __restrict__ b,
    float* Y, ushort* Yb, const float* qpos, ushort* Ypb, int relu)
{
  const int row = blockIdx.x*4 + (threadIdx.x>>6);
  const int lane = threadIdx.x & 63;
  if (row >= ROWS) return;
  float4 x = *(const float4*)(X + (size_t)row*xld + (lane<<2));
  if (R) { const float4 r = *(const float4*)(R + (size_t)row*256 + (lane<<2)); x.x+=r.x; x.y+=r.y; x.z+=r.z; x.w+=r.w; }
  float s = x.x+x.y+x.z+x.w;
  #pragma unroll
  for (int o=32;o>0;o>>=1) s += __shfl_xor(s,o);
  const float mean = s * (1.0f/256.0f);
  float4 d; d.x=x.x-mean; d.y=x.y-mean; d.z=x.z-mean; d.w=x.w-mean;
  float s2 = d.x*d.x+d.y*d.y+d.z*d.z+d.w*d.w;
  #pragma unroll
  for (int o=32;o>0;o>>=1) s2 += __shfl_xor(s2,o);
  const float rs = rsqrtf(s2*(1.0f/256.0f) + 1e-5f);
  const float4 wv = *(const float4*)(w + (lane<<2));
  const float4 bv = *(const float4*)(b + (lane<<2));
  float4 y;
  y.x = d.x*rs*wv.x + bv.x; y.y = d.y*rs*wv.y + bv.y;
  y.z = d.z*rs*wv.z + bv.z; y.w = d.w*rs*wv.w + bv.w;
  if (relu) { y.x=fmaxf(y.x,0.f); y.y=fmaxf(y.y,0.f); y.z=fmaxf(y.z,0.f); y.w=fmaxf(y.w,0.f); }
  if (Y)  *(float4*)(Y + (size_t)row*256 + (lane<<2)) = y;
  if (Yb) *(ushort4*)(Yb + (size_t)row*256 + (lane<<2)) = pk4(y);
  if (Ypb) {
    const float4 qp = *(const float4*)(qpos + (size_t)row*256 + (lane<<2));
    float4 zz; zz.x=y.x+qp.x; zz.y=y.y+qp.y; zz.z=y.z+qp.z; zz.w=y.w+qp.w;
    *(ushort4*)(Ypb + (size_t)row*256 + (lane<<2)) = pk4(zz);
  }
}

// ---------------------------------------------------------------------------
// Deformable gather -> rr row-major [row][2080] bf16.
// ---------------------------------------------------------------------------
__global__ __launch_bounds__(512) void gather_k(
    const ushort* __restrict__ bevb, const float* __restrict__ offaw,
    const float* __restrict__ ref, ushort* __restrict__ rr)
{
  const int row = blockIdx.x;
  const int h = threadIdx.x >> 6, lane = threadIdx.x & 63;
  const int b = row / NQQ;
  const float refx = ref[row*3+0], refy = ref[row*3+1];
  const float* oa = offaw + (size_t)row*96;
  float aw[4];
  {
    const float a0=oa[64+h*4+0], a1=oa[64+h*4+1], a2=oa[64+h*4+2], a3=oa[64+h*4+3];
    const float mx = fmaxf(fmaxf(a0,a1), fmaxf(a2,a3));
    const float e0=__expf(a0-mx), e1=__expf(a1-mx), e2=__expf(a2-mx), e3=__expf(a3-mx);
    const float inv = 1.0f/(e0+e1+e2+e3);
    aw[0]=e0*inv; aw[1]=e1*inv; aw[2]=e2*inv; aw[3]=e3*inv;
  }
  float r0=0.f, r1=0.f, r2=0.f, r3=0.f, sacc=0.f;
  const ushort* bb = bevb + (size_t)b*BEVH*BEVW*DD;
  #pragma unroll
  for (int p=0;p<4;++p) {
    const float ox = oa[h*8+p*2+0], oy = oa[h*8+p*2+1];
    const float x = (refx + ox*(1.0f/BEVW))*BEVW - 0.5f;
    const float y = (refy + oy*(1.0f/BEVH))*BEVH - 0.5f;
    const float x0f = floorf(x), y0f = floorf(y);
    const int x0 = (int)x0f, y0 = (int)y0f;
    const float fx = x - x0f, fy = y - y0f;
    #pragma unroll
    for (int dy=0;dy<2;++dy) {
      #pragma unroll
      for (int dx=0;dx<2;++dx) {
        const int xi = x0+dx, yi = y0+dy;
        if (xi < 0 || xi >= BEVW || yi < 0 || yi >= BEVH) continue;
        const float wgt = (dx ? fx : 1.0f-fx) * (dy ? fy : 1.0f-fy) * aw[p];
        const ushort4 g = *(const ushort4*)(bb + (size_t)(yi*BEVW + xi)*DD + (lane<<2));
        r0 += wgt*bf2f(g.x); r1 += wgt*bf2f(g.y);
        r2 += wgt*bf2f(g.z); r3 += wgt*bf2f(g.w);
        sacc += wgt;
      }
    }
  }
  ushort4 o;
  o.x = (ushort)f2bf1(r0); o.y = (ushort)f2bf1(r1);
  o.z = (ushort)f2bf1(r2); o.w = (ushort)f2bf1(r3);
  ushort* rrow = rr + (size_t)row*KDEF;
  *(ushort4*)&rrow[h*256 + (lane<<2)] = o;
  if (lane == 0) rrow[2048 + h] = (ushort)f2bf1(sacc);
  else if (lane < 4) rrow[2048 + lane*8 + h] = 0;
}

// ---------------------------------------------------------------------------
// One-time: Wfull[l][c][2080] = [ oproj@blockdiag(vproj) | Bmat | 0 ] in bf16
// ---------------------------------------------------------------------------
__global__ __launch_bounds__(256) void wcomb_k(
    const float* __restrict__ opw, const float* __restrict__ vpw,
    ushort* __restrict__ Wfull)
{
  const int l = blockIdx.z, h = blockIdx.y;
  const int ct = blockIdx.x & 3, kt = blockIdx.x >> 2;
  __shared__ float Ao[64][33];
  __shared__ float Bo[32][65];
  const int t = threadIdx.x;
  for (int i=t; i<2048; i+=256) {
    const int r = i>>5, j = i&31;
    Ao[r][j] = opw[(size_t)l*65536 + (size_t)(ct*64 + r)*256 + h*32 + j];
  }
  for (int i=t; i<2048; i+=256) {
    const int j = i>>6, kk = i&63;
    Bo[j][kk] = vpw[(size_t)l*65536 + (size_t)(h*32 + j)*256 + kt*64 + kk];
  }
  __syncthreads();
  const int tx = t&15, ty = t>>4;
  float acc[4][4] = {};
  for (int j=0;j<32;++j) {
    float a[4], bv[4];
    #pragma unroll
    for (int r=0;r<4;++r) a[r] = Ao[ty*4+r][j];
    #pragma unroll
    for (int cc=0;cc<4;++cc) bv[cc] = Bo[j][tx*4+cc];
    #pragma unroll
    for (int r=0;r<4;++r)
      #pragma unroll
      for (int cc=0;cc<4;++cc) acc[r][cc] += a[r]*bv[cc];
  }
  #pragma unroll
  for (int r=0;r<4;++r)
    #pragma unroll
    for (int cc=0;cc<4;++cc)
      Wfull[((size_t)l*256 + ct*64+ty*4+r)*KDEF + h*256 + kt*64 + tx*4+cc] = (ushort)f2bf1(acc[r][cc]);
}

__global__ void wcombB_k(const float* __restrict__ opw, const float* __restrict__ vpb,
                         ushort* __restrict__ Wfull)
{
  const int l = blockIdx.x; const int c = threadIdx.x;
  ushort* wr = Wfull + ((size_t)l*256 + c)*KDEF;
  for (int h=0; h<8; ++h) {
    float s = 0.f;
    for (int j=0;j<32;++j) s += opw[(size_t)l*65536 + (size_t)c*256 + h*32+j] * vpb[l*256 + h*32+j];
    wr[2048 + h] = (ushort)f2bf1(s);
  }
  for (int zz=2056; zz<KDEF; ++zz) wr[zz] = 0;
}

__global__ void init_k(const float* __restrict__ qe, float* __restrict__ qpos,
                       float* __restrict__ q, ushort* __restrict__ qb, ushort* __restrict__ qpb)
{
  const int t = blockIdx.x*blockDim.x + threadIdx.x;
  const int row = t >> 6; const int cc = (t & 63) << 2;
  const int n = row % NQQ;
  const float4 vp = *(const float4*)(qe + (size_t)n*512 + cc);
  const float4 vq = *(const float4*)(qe + (size_t)n*512 + 256 + cc);
  *(float4*)(qpos + (size_t)row*256 + cc) = vp;
  *(float4*)(q    + (size_t)row*256 + cc) = vq;
  *(ushort4*)(qb  + (size_t)row*256 + cc) = pk4(vq);
  float4 s; s.x=vq.x+vp.x; s.y=vq.y+vp.y; s.z=vq.z+vp.z; s.w=vq.w+vp.w;
  *(ushort4*)(qpb + (size_t)row*256 + cc) = pk4(s);
}

__global__ void prep_k(const float* __restrict__ ow, const float* __restrict__ ob,
                       const float* __restrict__ aw, const float* __restrict__ ab,
                       const float* __restrict__ rw, const float* __restrict__ rb,
                       const float* __restrict__ cw, const float* __restrict__ cb,
                       ushort* cwAb, float* cbA, ushort* cwBb, float* cbB)
{
  const int i = blockIdx.x*blockDim.x + threadIdx.x;
  if (i < 6*96*256) {
    const int l = i/(96*256), r = (i/256)%96, k = i%256;
    const float v = (r<64) ? ow[((size_t)l*64 + r)*256 + k] : aw[((size_t)l*32 + (r-64))*256 + k];
    cwAb[i] = (ushort)f2bf1(v);
  }
  if (i < 576) { const int l = i/96, r = i%96; cbA[i] = (r<64) ? ob[l*64+r] : ab[l*32 + r-64]; }
  if (i < 6*512*256) {
    const int l = i/(512*256), r = (i/256)%512, k = i%256;
    const float v = (r<256) ? rw[((size_t)l*256+r)*256+k] : cw[((size_t)l*256 + (r-256))*256 + k];
    cwBb[i] = (ushort)f2bf1(v);
  }
  if (i < 3072) { const int l = i/512, r = i%512; cbB[i] = (r<256) ? rb[l*256+r] : cb[l*256 + r-256]; }
}

__global__ void cvtw_k(const float* __restrict__ s1, const float* __restrict__ s2,
                       const float* __restrict__ s3, const float* __restrict__ s4,
                       const float* __restrict__ s5, const float* __restrict__ s6,
                       const float* __restrict__ s7, ushort* __restrict__ dst)
{
  const int i4 = (blockIdx.x*256 + threadIdx.x)*4;
  if (i4 >= 4325376) return;
  const float* src; int lo;
  if      (i4 < 1179648) { src=s1; lo=i4; }
  else if (i4 < 1572864) { src=s2; lo=i4-1179648; }
  else if (i4 < 1966080) { src=s3; lo=i4-1572864; }
  else if (i4 < 2752512) { src=s4; lo=i4-1966080; }
  else if (i4 < 3538944) { src=s5; lo=i4-2752512; }
  else if (i4 < 3932160) { src=s6; lo=i4-3538944; }
  else                   { src=s7; lo=i4-3932160; }
  const float4 v = *(const float4*)(src+lo);
  *(ushort4*)(dst+i4) = pk4(v);
}

__global__ void cvtbev_k(const float* __restrict__ bev, ushort* __restrict__ bevb)
{
  const size_t i = ((size_t)blockIdx.x*256 + threadIdx.x)*8;
  const float4 a = *(const float4*)(bev+i);
  const float4 b = *(const float4*)(bev+i+4);
  *(ushort4*)(bevb+i)   = pk4(a);
  *(ushort4*)(bevb+i+4) = pk4(b);
}

extern "C" void kernel_launch(void* const* d_in, const int* in_sizes, int n_in,
                              void* d_out, int out_size, void* d_ws, size_t ws_size,
                              hipStream_t stream)
{
  const float* bev      = (const float*)d_in[0];
  const float* qe       = (const float*)d_in[1];
  const float* ref_w    = (const float*)d_in[2];
  const float* ref_b    = (const float*)d_in[3];
  const float* sa_in_w  = (const float*)d_in[4];
  const float* sa_in_b  = (const float*)d_in[5];
  const float* sa_out_w = (const float*)d_in[6];
  const float* sa_out_b = (const float*)d_in[7];
  const float* ln_w     = (const float*)d_in[8];
  const float* ln_b     = (const float*)d_in[9];
  const float* off_w    = (const float*)d_in[10];
  const float* off_b    = (const float*)d_in[11];
  const float* aw_w     = (const float*)d_in[12];
  const float* aw_b     = (const float*)d_in[13];
  const float* vproj_w  = (const float*)d_in[14];
  const float* vproj_b  = (const float*)d_in[15];
  const float* oproj_w  = (const float*)d_in[16];
  const float* oproj_b  = (const float*)d_in[17];
  const float* ffn_w1   = (const float*)d_in[18];
  const float* ffn_b1   = (const float*)d_in[19];
  const float* ffn_w2   = (const float*)d_in[20];
  const float* ffn_b2   = (const float*)d_in[21];
  const float* reg_w1   = (const float*)d_in[22];
  const float* reg_b1   = (const float*)d_in[23];
  const float* reg_w2   = (const float*)d_in[24];
  const float* reg_b2   = (const float*)d_in[25];
  const float* reg_w3   = (const float*)d_in[26];
  const float* reg_b3   = (const float*)d_in[27];
  const float* cls_w1   = (const float*)d_in[28];
  const float* cls_b1   = (const float*)d_in[29];
  const float* cls_w2   = (const float*)d_in[30];
  const float* cls_b2   = (const float*)d_in[31];
  const float* cls_w3   = (const float*)d_in[32];
  const float* cls_b3   = (const float*)d_in[33];
  const float* cls_ln_w = (const float*)d_in[34];
  const float* cls_ln_b = (const float*)d_in[35];
  float* out = (float*)d_out;

  float* ws    = (float*)d_ws;
  float* qpos  = ws;                    // 921600
  float* q     = qpos + 921600;
  float* tA    = q    + 921600;         // temp
  float* tB    = tA   + 921600;         // temp
  float* rc2   = tB   + 921600;         // (unused now)
  float* cls1f = rc2  + 1843200;        // (unused)
  float* offaw = cls1f+ 921600;         // 345600
  float* ref   = offaw+ 345600;         // 10800
  float* cbA   = ref  + 10800;          // 576
  float* cbB   = cbA  + 576;            // 3072
  ushort* usb  = (ushort*)(ws + 6811248);
  ushort* rr   = usb;                   // 7488000 = 3600*2080 (aliases below)
  ushort* QKb  = usb;                   // 1843200
  ushort* Vb   = usb + 1843200;         // 921600
  ushort* tAb  = usb + 2764800;         // 921600
  ushort* W5b  = usb + 3686400;         // 1843200
  ushort* qb   = usb + 7488000;         // 921600
  ushort* qpb  = usb + 8409600;         // 921600
  ushort* bevb = usb + 9331200;         // 40960000
  ushort* wbf  = usb + 50291200;
  ushort* siwb = wbf;                   // 1179648
  ushort* sowb = wbf + 1179648;         // 393216
  ushort* f1wb = wbf + 1966080;         // 786432
  ushort* f2wb = wbf + 2752512;         // 786432
  ushort* r2wb = wbf + 3538944;         // 393216
  ushort* c2wb = wbf + 3932160;         // 393216
  ushort* cwAb = wbf + 4325376;         // 147456
  ushort* cwBb = wbf + 4472832;         // 786432
  ushort* Wfull= wbf + 5259264;         // 3194880 = 6*256*2080

  auto G = [&](int BM, const ushort* A0, const ushort* A1, int NA, int lda,
               const ushort* W0, const ushort* W1, int NW,
               const float* B0, const float* B1, int NB,
               void* Y0, int ldy0, int obf0,
               void* Y1, int ldy1, int obf1, int NY,
               int M, int N, int K, int reluN) {
    dim3 grid((M+BM-1)/BM, (N+63)/64);
    if (BM==64)
      gemmb_k<64><<<grid, 256, 0, stream>>>(A0,A1,NA,lda,W0,W1,NW,B0,B1,NB,
                                            Y0,ldy0,obf0,Y1,ldy1,obf1,NY,M,N,K,reluN);
    else
      gemmb_k<32><<<grid, 256, 0, stream>>>(A0,A1,NA,lda,W0,W1,NW,B0,B1,NB,
                                            Y0,ldy0,obf0,Y1,ldy1,obf1,NY,M,N,K,reluN);
  };

  // one-time converts + prep
  cvtbev_k<<<20000, 256, 0, stream>>>(bev, bevb);
  cvtw_k<<<4224, 256, 0, stream>>>(sa_in_w, sa_out_w, oproj_w, ffn_w1, ffn_w2, reg_w2, cls_w2, wbf);
  prep_k<<<3072, 256, 0, stream>>>(off_w, off_b, aw_w, aw_b, reg_w1, reg_b1, cls_w1, cls_b1,
                                   cwAb, cbA, cwBb, cbB);
  wcomb_k<<<dim3(16,8,6), 256, 0, stream>>>(oproj_w, vproj_w, Wfull);
  wcombB_k<<<6, 256, 0, stream>>>(oproj_w, vproj_b, Wfull);
  init_k<<<900, 256, 0, stream>>>(qe, qpos, q, qb, qpb);
  {
    dim3 grid((ROWS+63)/64, 1);
    gemm_k<<<grid, 256, 0, stream>>>(qpos, 256, ref_w, ref_b, ref, ROWS, 3, 256, 3, 2);
  }

  for (int i=0;i<NLAYER;++i) {
    const float* sib = sa_in_b + (size_t)i*768;
    const ushort* siw = siwb + (size_t)i*196608;
    // ---- self-attention: fused QKV ----
    G(64, qpb, qb, 512, 256, siw, siw, BIGN, sib, sib, BIGN,
      QKb, 512, 1, Vb, 256, 1, 512, ROWS, 768, 256, 0);
    attn3_k<<<dim3(32,15), 256, 0, stream>>>(QKb, Vb, tAb);
    G(32, tAb, tAb, BIGN, 256, sowb + (size_t)i*65536, nullptr, BIGN,
      sa_out_b + (size_t)i*256, nullptr, BIGN,
      tB, 256, 0, nullptr, 0, 0, BIGN, ROWS, 256, 256, 0);
    ln_k<<<900, 256, 0, stream>>>(tB, 256, q, ln_w + (size_t)(i*3+0)*256, ln_b + (size_t)(i*3+0)*256,
                                  q, nullptr, qpos, qpb, 0);
    // ---- deformable cross-attention (gather + fused Wcomb gemm) ----
    G(32, qpb, qpb, BIGN, 256, cwAb + (size_t)i*24576, nullptr, BIGN,
      cbA + i*96, nullptr, BIGN,
      offaw, 96, 0, nullptr, 0, 0, BIGN, ROWS, 96, 256, 0);
    gather_k<<<ROWS, 512, 0, stream>>>(bevb, offaw, ref, rr);
    G(32, rr, rr, BIGN, KDEF, Wfull + (size_t)i*256*KDEF, nullptr, BIGN,
      oproj_b + (size_t)i*256, nullptr, BIGN,
      tA, 256, 0, nullptr, 0, 0, BIGN, ROWS, 256, KDEF, 0);
    ln_k<<<900, 256, 0, stream>>>(tA, 256, q, ln_w + (size_t)(i*3+1)*256, ln_b + (size_t)(i*3+1)*256,
                                  q, qb, nullptr, nullptr, 0);
    // ---- FFN ----
    G(64, qb, qb, BIGN, 256, f1wb + (size_t)i*131072, nullptr, BIGN,
      ffn_b1 + (size_t)i*512, nullptr, BIGN,
      W5b, 512, 1, nullptr, 0, 0, BIGN, ROWS, 512, 256, 512);
    G(32, W5b, W5b, BIGN, 512, f2wb + (size_t)i*131072, nullptr, BIGN,
      ffn_b2 + (size_t)i*256, nullptr, BIGN,
      tA, 256, 0, nullptr, 0, 0, BIGN, ROWS, 256, 512, 0);
    ln_k<<<900, 256, 0, stream>>>(tA, 256, q, ln_w + (size_t)(i*3+2)*256, ln_b + (size_t)(i*3+2)*256,
                                  q, qb, qpos, qpb, 0);
    // ---- fused tail: reg1|cls1 + clsLN1 + reg2|cls2 + clsLN2 + heads + refout ----
    tail_k<<<225, 256, 0, stream>>>(qb,
        cwBb + (size_t)i*131072, cbB + i*512,
        cls_ln_w + (size_t)(i*2+0)*256, cls_ln_b + (size_t)(i*2+0)*256,
        r2wb + (size_t)i*65536, c2wb + (size_t)i*65536,
        reg_b2 + (size_t)i*256, cls_b2 + (size_t)i*256,
        cls_ln_w + (size_t)(i*2+1)*256, cls_ln_b + (size_t)(i*2+1)*256,
        reg_w3 + (size_t)i*2560, reg_b3 + (size_t)i*10,
        cls_w3 + (size_t)i*2560, cls_b3 + (size_t)i*10,
        ref, out + (size_t)i*ROWS*20);
  }
}

// Round 11
// 1171.680 us; speedup vs baseline: 1.1429x; 1.1429x over previous
//
#include <hip/hip_runtime.h>
#include <math.h>

#define DD 256
#define NQQ 900
#define NBS 4
#define NLAYER 6
#define BEVH 200
#define BEVW 200
#define ROWS (NBS*NQQ)   // 3600
#define BIGN (1<<30)
#define KDEF 2080        // deform fused K: 2048 + 8 sacc + 24 zero

typedef __attribute__((ext_vector_type(8))) short bf16x8;
typedef __attribute__((ext_vector_type(4))) float f32x4;

__device__ __forceinline__ float sigmoidf_(float x){ return 1.0f/(1.0f+expf(-x)); }
__device__ __forceinline__ float invsigf_(float x){
  x = fminf(fmaxf(x,0.0f),1.0f);
  float lo = fmaxf(x,1e-5f), hi = fmaxf(1.0f-x,1e-5f);
  return logf(lo/hi);
}
__device__ __forceinline__ unsigned f2bf1(float x){
  unsigned u = __float_as_uint(x);
  return (u + 0x7fffu + ((u>>16)&1u)) >> 16;
}
__device__ __forceinline__ unsigned pk2(float a, float b){
  return f2bf1(a) | (f2bf1(b)<<16);
}
__device__ __forceinline__ float bf2f(unsigned u){ return __uint_as_float(u<<16); }
__device__ __forceinline__ ushort4 pk4(float4 y){
  ushort4 o; o.x=(ushort)f2bf1(y.x); o.y=(ushort)f2bf1(y.y);
  o.z=(ushort)f2bf1(y.z); o.w=(ushort)f2bf1(y.w); return o;
}

// ---------------------------------------------------------------------------
// fp32 GEMM (ref head only).
// ---------------------------------------------------------------------------
__global__ __launch_bounds__(256) void gemm_k(
    const float* __restrict__ A, int lda,
    const float* __restrict__ W, const float* __restrict__ B,
    float* __restrict__ Y, int M, int N, int K, int ldy, int act)
{
  __shared__ float As[2][32][66];
  __shared__ float Ws[2][32][66];
  const int t = threadIdx.x;
  const int m0 = blockIdx.x*64, n0 = blockIdx.y*64;
  const int lr = t >> 2, kq = (t & 3) << 3;
  const int tx = t & 15, ty = t >> 4;
  const bool aok = (m0 + lr) < M;
  const bool wok = (n0 + lr) < N;
  const float* ap  = A + (size_t)(m0+lr)*lda + kq;
  const float* wp  = W + (size_t)(n0+lr)*K + kq;
  float4 pa[2], pw[2];
  auto loadch = [&](int kc) {
    #pragma unroll
    for (int i=0;i<2;++i) {
      pa[i] = aok ? *(const float4*)(ap + kc + i*4) : make_float4(0,0,0,0);
      pw[i] = wok ? *(const float4*)(wp + kc + i*4) : make_float4(0,0,0,0);
    }
  };
  auto storech = [&](int bf) {
    #pragma unroll
    for (int i=0;i<2;++i) {
      const int kk = kq + i*4;
      As[bf][kk+0][lr]=pa[i].x; As[bf][kk+1][lr]=pa[i].y;
      As[bf][kk+2][lr]=pa[i].z; As[bf][kk+3][lr]=pa[i].w;
      Ws[bf][kk+0][lr]=pw[i].x; Ws[bf][kk+1][lr]=pw[i].y;
      Ws[bf][kk+2][lr]=pw[i].z; Ws[bf][kk+3][lr]=pw[i].w;
    }
  };
  float acc[4][4] = {};
  loadch(0); storech(0); __syncthreads();
  const int NC = K >> 5;
  for (int c=0; c<NC; ++c) {
    if (c+1 < NC) loadch((c+1) << 5);
    const int bf = c & 1;
    #pragma unroll
    for (int k=0;k<32;++k) {
      const float4 a4 = *(const float4*)&As[bf][k][ty<<2];
      const float4 w4 = *(const float4*)&Ws[bf][k][tx<<2];
      const float av[4] = {a4.x,a4.y,a4.z,a4.w};
      const float wv[4] = {w4.x,w4.y,w4.z,w4.w};
      #pragma unroll
      for (int r=0;r<4;++r)
        #pragma unroll
        for (int cc=0;cc<4;++cc) acc[r][cc] += av[r]*wv[cc];
    }
    if (c+1 < NC) { storech((c+1)&1); __syncthreads(); }
  }
  const int gn0 = n0 + (tx<<2);
  #pragma unroll
  for (int r=0;r<4;++r) {
    const int gm = m0 + (ty<<2) + r;
    if (gm >= M) continue;
    for (int cc=0; cc<4 && gn0+cc<N; ++cc) {
      float x = acc[r][cc] + (B ? B[gn0+cc] : 0.0f);
      if (act==1) x = fmaxf(x,0.0f);
      else if (act==2) x = sigmoidf_(x);
      Y[(size_t)gm*ldy + gn0+cc] = x;
    }
  }
}

// ---------------------------------------------------------------------------
// bf16 MFMA GEMM v3: templated BM (64 or 32), BN=64. Dual-A/W/bias/Y.
// ---------------------------------------------------------------------------
template<int BM>
__global__ __launch_bounds__(256) void gemmb_k(
    const ushort* __restrict__ A0, const ushort* __restrict__ A1, int NA, int lda,
    const ushort* __restrict__ W0, const ushort* __restrict__ W1, int NW,
    const float* __restrict__ B0, const float* __restrict__ B1, int NB,
    void* __restrict__ Y0, int ldy0, int obf0,
    void* __restrict__ Y1, int ldy1, int obf1, int NY,
    int M, int N, int K, int reluN)
{
  __shared__ ushort As[2][BM*32];
  __shared__ ushort Bs[2][2048];
  const int t = threadIdx.x;
  const int m0 = blockIdx.x*BM, n0 = blockIdx.y*64;
  const ushort* A = (n0 < NA) ? A0 : A1;
  const int srow = t>>2, scb = t&3;
  const int wrow = n0 + srow;
  const bool wok = wrow < N;
  const ushort* wp = (wrow < NW) ? (W0 + (size_t)wrow*K + scb*8)
                                 : (W1 + (size_t)(wrow-NW)*K + scb*8);
  bool aok; const ushort* ap;
  if constexpr (BM==64) { aok = (m0+srow)<M; }
  else { aok = (t<128) && (m0+srow)<M; }
  ap = A + (size_t)(m0 + (aok?srow:0))*lda + scb*8;
  const int sidx = srow*32 + ((scb ^ (srow&3))<<3);
  const bf16x8 zf = {0,0,0,0,0,0,0,0};

  bf16x8 pa, pw;
  auto loadg = [&](int kc){
    pa = aok ? *(const bf16x8*)(ap+kc) : zf;
    pw = wok ? *(const bf16x8*)(wp+kc) : zf;
  };
  auto writes = [&](int bf){
    if (BM==64 || t<128) *(bf16x8*)&As[bf][sidx] = pa;
    *(bf16x8*)&Bs[bf][sidx] = pw;
  };

  const int wv = t>>6, lane = t&63;
  const int fm = lane&15, kb = lane>>4;

  auto writeout = [&](float x, int row, int col){
    if (row >= M || col >= N) return;
    if (col < reluN) x = fmaxf(x, 0.0f);
    if (col < NY) {
      if (obf0) ((ushort*)Y0)[(size_t)row*ldy0 + col] = (ushort)f2bf1(x);
      else      ((float*)Y0)[(size_t)row*ldy0 + col] = x;
    } else {
      const int c2 = col - NY;
      if (obf1) ((ushort*)Y1)[(size_t)row*ldy1 + c2] = (ushort)f2bf1(x);
      else      ((float*)Y1)[(size_t)row*ldy1 + c2] = x;
    }
  };

  const int NS = K>>5;
  if constexpr (BM==64) {
    const int wr = wv>>1, wc = wv&1;
    const int arow0 = wr*32 + fm, arow1 = arow0 + 16;
    const int bcol0 = wc*32 + fm, bcol1 = bcol0 + 16;
    const int ai0 = arow0*32 + ((kb^(arow0&3))<<3);
    const int ai1 = arow1*32 + ((kb^(arow1&3))<<3);
    const int bi0 = bcol0*32 + ((kb^(bcol0&3))<<3);
    const int bi1 = bcol1*32 + ((kb^(bcol1&3))<<3);
    f32x4 acc00={0,0,0,0}, acc01={0,0,0,0}, acc10={0,0,0,0}, acc11={0,0,0,0};
    loadg(0); writes(0); __syncthreads();
    for (int s=0; s<NS; ++s) {
      if (s+1<NS) loadg((s+1)<<5);
      const int bf = s&1;
      bf16x8 a0 = *(bf16x8*)&As[bf][ai0];
      bf16x8 a1 = *(bf16x8*)&As[bf][ai1];
      bf16x8 b0 = *(bf16x8*)&Bs[bf][bi0];
      bf16x8 b1 = *(bf16x8*)&Bs[bf][bi1];
      acc00 = __builtin_amdgcn_mfma_f32_16x16x32_bf16(a0,b0,acc00,0,0,0);
      acc01 = __builtin_amdgcn_mfma_f32_16x16x32_bf16(a0,b1,acc01,0,0,0);
      acc10 = __builtin_amdgcn_mfma_f32_16x16x32_bf16(a1,b0,acc10,0,0,0);
      acc11 = __builtin_amdgcn_mfma_f32_16x16x32_bf16(a1,b1,acc11,0,0,0);
      if (s+1<NS) { __syncthreads(); writes((s+1)&1); __syncthreads(); }
    }
    #pragma unroll
    for (int fr=0; fr<2; ++fr)
      #pragma unroll
      for (int fc=0; fc<2; ++fc) {
        const f32x4 av = fr ? (fc ? acc11 : acc10) : (fc ? acc01 : acc00);
        const int col = n0 + wc*32 + fc*16 + fm;
        const float bias = (col<N) ? ((col<NB) ? B0[col] : B1[col-NB]) : 0.0f;
        #pragma unroll
        for (int r=0; r<4; ++r)
          writeout(av[r] + bias, m0 + wr*32 + fr*16 + kb*4 + r, col);
      }
  } else {
    const int ai0 = fm*32 + ((kb^(fm&3))<<3);
    const int ai1 = (fm+16)*32 + ((kb^(fm&3))<<3);
    const int bcol = wv*16 + fm;
    const int bi = bcol*32 + ((kb^(bcol&3))<<3);
    f32x4 acc0={0,0,0,0}, acc1={0,0,0,0};
    loadg(0); writes(0); __syncthreads();
    for (int s=0; s<NS; ++s) {
      if (s+1<NS) loadg((s+1)<<5);
      const int bf = s&1;
      bf16x8 a0 = *(bf16x8*)&As[bf][ai0];
      bf16x8 a1 = *(bf16x8*)&As[bf][ai1];
      bf16x8 b  = *(bf16x8*)&Bs[bf][bi];
      acc0 = __builtin_amdgcn_mfma_f32_16x16x32_bf16(a0,b,acc0,0,0,0);
      acc1 = __builtin_amdgcn_mfma_f32_16x16x32_bf16(a1,b,acc1,0,0,0);
      if (s+1<NS) { __syncthreads(); writes((s+1)&1); __syncthreads(); }
    }
    const int col = n0 + wv*16 + fm;
    const float bias = (col<N) ? ((col<NB) ? B0[col] : B1[col-NB]) : 0.0f;
    #pragma unroll
    for (int r=0; r<4; ++r) {
      writeout(acc0[r] + bias, m0 + kb*4 + r, col);
      writeout(acc1[r] + bias, m0 + 16 + kb*4 + r, col);
    }
  }
}

// ---------------------------------------------------------------------------
// MFMA bf16 flash attention v2: block-shared LDS K/V staging (4 waves share
// one (b,h)); K row-major pitch 40, V transposed pitch 34; double-buffered.
// ---------------------------------------------------------------------------
__global__ __launch_bounds__(256) void attn3_k(
    const ushort* __restrict__ QKb, const ushort* __restrict__ Vb, ushort* __restrict__ Ob)
{
  const int b = blockIdx.x >> 3, h = blockIdx.x & 7;
  const int wv = threadIdx.x >> 6, lane = threadIdx.x & 63;
  const int t = threadIdx.x;
  const int qt = blockIdx.y*64 + wv*16;
  const int lq = lane & 15, lg = lane >> 4;
  const int q = qt + lq;

  __shared__ ushort Ks[2][32*40];
  __shared__ ushort Vt[2][32*34];

  bf16x8 qf = *(const bf16x8*)(QKb + (size_t)(b*NQQ + min(q, NQQ-1))*512 + h*32 + lg*8);
  f32x4 ot0 = {0.f,0.f,0.f,0.f}, ot1 = {0.f,0.f,0.f,0.f};
  float m = -3e38f, l = 0.0f;

  const ushort* kg = QKb + (size_t)b*NQQ*512 + 256 + h*32;
  const ushort* vg = Vb  + (size_t)b*NQQ*256 + h*32;
  const int srow = t>>3, sc4 = (t&7)*4;

  ushort4 kv, vv;
  auto sload = [&](int k0){
    const int gr = min(k0 + srow, NQQ-1);
    kv = *(const ushort4*)(kg + (size_t)gr*512 + sc4);
    vv = *(const ushort4*)(vg + (size_t)gr*256 + sc4);
  };
  auto swrite = [&](int bf){
    *(ushort4*)&Ks[bf][srow*40 + sc4] = kv;
    Vt[bf][(sc4+0)*34 + srow] = vv.x;
    Vt[bf][(sc4+1)*34 + srow] = vv.y;
    Vt[bf][(sc4+2)*34 + srow] = vv.z;
    Vt[bf][(sc4+3)*34 + srow] = vv.w;
  };

  const int pbase = (lq + ((lg&1)<<5)) << 2;
  const bool hiC = (lg >> 1);
  const int NC = (NQQ + 31) >> 5;   // 29

  sload(0); swrite(0); __syncthreads();
  for (int c = 0; c < NC; ++c) {
    const int k0 = c<<5;
    if (c+1 < NC) sload((c+1)<<5);
    const int bf = c&1;
    bf16x8 kf0 = *(bf16x8*)&Ks[bf][lq*40 + lg*8];
    bf16x8 kf1 = *(bf16x8*)&Ks[bf][(16+lq)*40 + lg*8];
    const f32x4 z = {0.f,0.f,0.f,0.f};
    f32x4 s0 = __builtin_amdgcn_mfma_f32_16x16x32_bf16(kf0, qf, z, 0, 0, 0);
    f32x4 s1 = __builtin_amdgcn_mfma_f32_16x16x32_bf16(kf1, qf, z, 0, 0, 0);
    const float sc = 0.17677669529663687f;
    float p0[4], p1[4];
    #pragma unroll
    for (int r=0;r<4;++r) { p0[r] = s0[r]*sc; p1[r] = s1[r]*sc; }
    if (k0 + 32 > NQQ) {
      #pragma unroll
      for (int r=0;r<4;++r) {
        if (k0 + 4*lg + r      >= NQQ) p0[r] = -3e38f;
        if (k0 + 16 + 4*lg + r >= NQQ) p1[r] = -3e38f;
      }
    }
    float cm = fmaxf(fmaxf(fmaxf(p0[0],p0[1]),fmaxf(p0[2],p0[3])),
                     fmaxf(fmaxf(p1[0],p1[1]),fmaxf(p1[2],p1[3])));
    cm = fmaxf(cm, __shfl_xor(cm, 16));
    cm = fmaxf(cm, __shfl_xor(cm, 32));
    const float mn = fmaxf(m, cm);
    const float corr = __expf(m - mn);
    m = mn;
    float rs = 0.0f;
    #pragma unroll
    for (int r=0;r<4;++r) { p0[r] = __expf(p0[r]-mn); rs += p0[r]; }
    #pragma unroll
    for (int r=0;r<4;++r) { p1[r] = __expf(p1[r]-mn); rs += p1[r]; }
    rs += __shfl_xor(rs, 16);
    rs += __shfl_xor(rs, 32);
    l = l*corr + rs;
    ot0 *= corr; ot1 *= corr;

    const int c00 = (int)pk2(p0[0],p0[1]), c01 = (int)pk2(p0[2],p0[3]);
    const int c10 = (int)pk2(p1[0],p1[1]), c11 = (int)pk2(p1[2],p1[3]);
    const int A0 = __builtin_amdgcn_ds_bpermute(pbase,    c00);
    const int B0 = __builtin_amdgcn_ds_bpermute(pbase,    c10);
    const int A1 = __builtin_amdgcn_ds_bpermute(pbase,    c01);
    const int B1 = __builtin_amdgcn_ds_bpermute(pbase,    c11);
    const int A2 = __builtin_amdgcn_ds_bpermute(pbase+64, c00);
    const int B2 = __builtin_amdgcn_ds_bpermute(pbase+64, c10);
    const int A3 = __builtin_amdgcn_ds_bpermute(pbase+64, c01);
    const int B3 = __builtin_amdgcn_ds_bpermute(pbase+64, c11);
    union { bf16x8 v; int u[4]; } pv;
    pv.u[0] = hiC ? B0 : A0; pv.u[1] = hiC ? B1 : A1;
    pv.u[2] = hiC ? B2 : A2; pv.u[3] = hiC ? B3 : A3;

    bf16x8 vf0, vf1;
    {
      union { bf16x8 v; unsigned u[4]; } u0, u1;
      const int rb = 8*lg;
      #pragma unroll
      for (int jj=0;jj<4;++jj) {
        u0.u[jj] = *(const unsigned*)&Vt[bf][lq*34 + rb + 2*jj];
        u1.u[jj] = *(const unsigned*)&Vt[bf][(16+lq)*34 + rb + 2*jj];
      }
      vf0 = u0.v; vf1 = u1.v;
    }
    ot0 = __builtin_amdgcn_mfma_f32_16x16x32_bf16(vf0, pv.v, ot0, 0, 0, 0);
    ot1 = __builtin_amdgcn_mfma_f32_16x16x32_bf16(vf1, pv.v, ot1, 0, 0, 0);
    if (c+1 < NC) { __syncthreads(); swrite((c+1)&1); __syncthreads(); }
  }
  if (q < NQQ && qt < NQQ) {
    const float inv = 1.0f / l;
    ushort* op = Ob + (size_t)(b*NQQ + q)*256 + h*32;
    uint2 w0, w1;
    w0.x = pk2(ot0[0]*inv, ot0[1]*inv); w0.y = pk2(ot0[2]*inv, ot0[3]*inv);
    w1.x = pk2(ot1[0]*inv, ot1[1]*inv); w1.y = pk2(ot1[2]*inv, ot1[3]*inv);
    *(uint2*)(op + 4*lg)      = w0;
    *(uint2*)(op + 16 + 4*lg) = w1;
  }
}

// ---------------------------------------------------------------------------
// LayerNorm: optional f32 out, bf16 out, bf16(out+qpos) out.
// ---------------------------------------------------------------------------
__global__ __launch_bounds__(256) void ln_k(
    const float* X, int xld, const float* R,
    const float* __restrict__ w, const float* __restrict__ b,
    float* Y, ushort* Yb, const float* qpos, ushort* Ypb, int relu)
{
  const int row = blockIdx.x*4 + (threadIdx.x>>6);
  const int lane = threadIdx.x & 63;
  if (row >= ROWS) return;
  float4 x = *(const float4*)(X + (size_t)row*xld + (lane<<2));
  if (R) { const float4 r = *(const float4*)(R + (size_t)row*256 + (lane<<2)); x.x+=r.x; x.y+=r.y; x.z+=r.z; x.w+=r.w; }
  float s = x.x+x.y+x.z+x.w;
  #pragma unroll
  for (int o=32;o>0;o>>=1) s += __shfl_xor(s,o);
  const float mean = s * (1.0f/256.0f);
  float4 d; d.x=x.x-mean; d.y=x.y-mean; d.z=x.z-mean; d.w=x.w-mean;
  float s2 = d.x*d.x+d.y*d.y+d.z*d.z+d.w*d.w;
  #pragma unroll
  for (int o=32;o>0;o>>=1) s2 += __shfl_xor(s2,o);
  const float rs = rsqrtf(s2*(1.0f/256.0f) + 1e-5f);
  const float4 wv = *(const float4*)(w + (lane<<2));
  const float4 bv = *(const float4*)(b + (lane<<2));
  float4 y;
  y.x = d.x*rs*wv.x + bv.x; y.y = d.y*rs*wv.y + bv.y;
  y.z = d.z*rs*wv.z + bv.z; y.w = d.w*rs*wv.w + bv.w;
  if (relu) { y.x=fmaxf(y.x,0.f); y.y=fmaxf(y.y,0.f); y.z=fmaxf(y.z,0.f); y.w=fmaxf(y.w,0.f); }
  if (Y)  *(float4*)(Y + (size_t)row*256 + (lane<<2)) = y;
  if (Yb) *(ushort4*)(Yb + (size_t)row*256 + (lane<<2)) = pk4(y);
  if (Ypb) {
    const float4 qp = *(const float4*)(qpos + (size_t)row*256 + (lane<<2));
    float4 zz; zz.x=y.x+qp.x; zz.y=y.y+qp.y; zz.z=y.z+qp.z; zz.w=y.w+qp.w;
    *(ushort4*)(Ypb + (size_t)row*256 + (lane<<2)) = pk4(zz);
  }
}

// ---------------------------------------------------------------------------
// Deformable gather -> rr row-major [row][2080] bf16 (2048 feat | 8 sacc | 24 z)
// ---------------------------------------------------------------------------
__global__ __launch_bounds__(512) void gather_k(
    const ushort* __restrict__ bevb, const float* __restrict__ offaw,
    const float* __restrict__ ref, ushort* __restrict__ rr)
{
  const int row = blockIdx.x;
  const int h = threadIdx.x >> 6, lane = threadIdx.x & 63;
  const int b = row / NQQ;
  const float refx = ref[row*3+0], refy = ref[row*3+1];
  const float* oa = offaw + (size_t)row*96;
  float aw[4];
  {
    const float a0=oa[64+h*4+0], a1=oa[64+h*4+1], a2=oa[64+h*4+2], a3=oa[64+h*4+3];
    const float mx = fmaxf(fmaxf(a0,a1), fmaxf(a2,a3));
    const float e0=__expf(a0-mx), e1=__expf(a1-mx), e2=__expf(a2-mx), e3=__expf(a3-mx);
    const float inv = 1.0f/(e0+e1+e2+e3);
    aw[0]=e0*inv; aw[1]=e1*inv; aw[2]=e2*inv; aw[3]=e3*inv;
  }
  float r0=0.f, r1=0.f, r2=0.f, r3=0.f, sacc=0.f;
  const ushort* bb = bevb + (size_t)b*BEVH*BEVW*DD;
  #pragma unroll
  for (int p=0;p<4;++p) {
    const float ox = oa[h*8+p*2+0], oy = oa[h*8+p*2+1];
    const float x = (refx + ox*(1.0f/BEVW))*BEVW - 0.5f;
    const float y = (refy + oy*(1.0f/BEVH))*BEVH - 0.5f;
    const float x0f = floorf(x), y0f = floorf(y);
    const int x0 = (int)x0f, y0 = (int)y0f;
    const float fx = x - x0f, fy = y - y0f;
    #pragma unroll
    for (int dy=0;dy<2;++dy) {
      #pragma unroll
      for (int dx=0;dx<2;++dx) {
        const int xi = x0+dx, yi = y0+dy;
        if (xi < 0 || xi >= BEVW || yi < 0 || yi >= BEVH) continue;
        const float wgt = (dx ? fx : 1.0f-fx) * (dy ? fy : 1.0f-fy) * aw[p];
        const ushort4 g = *(const ushort4*)(bb + (size_t)(yi*BEVW + xi)*DD + (lane<<2));
        r0 += wgt*bf2f(g.x); r1 += wgt*bf2f(g.y);
        r2 += wgt*bf2f(g.z); r3 += wgt*bf2f(g.w);
        sacc += wgt;
      }
    }
  }
  ushort4 o;
  o.x = (ushort)f2bf1(r0); o.y = (ushort)f2bf1(r1);
  o.z = (ushort)f2bf1(r2); o.w = (ushort)f2bf1(r3);
  ushort* rrow = rr + (size_t)row*KDEF;
  *(ushort4*)&rrow[h*256 + (lane<<2)] = o;
  if (lane == 0) rrow[2048 + h] = (ushort)f2bf1(sacc);
  else if (lane < 4) rrow[2048 + lane*8 + h] = 0;
}

// ---------------------------------------------------------------------------
// One-time: Wfull[l][c][2080] = [ oproj@blockdiag(vproj) | Bmat | 0 ] in bf16
// ---------------------------------------------------------------------------
__global__ __launch_bounds__(256) void wcomb_k(
    const float* __restrict__ opw, const float* __restrict__ vpw,
    ushort* __restrict__ Wfull)
{
  const int l = blockIdx.z, h = blockIdx.y;
  const int ct = blockIdx.x & 3, kt = blockIdx.x >> 2;
  __shared__ float Ao[64][33];
  __shared__ float Bo[32][65];
  const int t = threadIdx.x;
  for (int i=t; i<2048; i+=256) {
    const int r = i>>5, j = i&31;
    Ao[r][j] = opw[(size_t)l*65536 + (size_t)(ct*64 + r)*256 + h*32 + j];
  }
  for (int i=t; i<2048; i+=256) {
    const int j = i>>6, kk = i&63;
    Bo[j][kk] = vpw[(size_t)l*65536 + (size_t)(h*32 + j)*256 + kt*64 + kk];
  }
  __syncthreads();
  const int tx = t&15, ty = t>>4;
  float acc[4][4] = {};
  for (int j=0;j<32;++j) {
    float a[4], bv[4];
    #pragma unroll
    for (int r=0;r<4;++r) a[r] = Ao[ty*4+r][j];
    #pragma unroll
    for (int cc=0;cc<4;++cc) bv[cc] = Bo[j][tx*4+cc];
    #pragma unroll
    for (int r=0;r<4;++r)
      #pragma unroll
      for (int cc=0;cc<4;++cc) acc[r][cc] += a[r]*bv[cc];
  }
  #pragma unroll
  for (int r=0;r<4;++r)
    #pragma unroll
    for (int cc=0;cc<4;++cc)
      Wfull[((size_t)l*256 + ct*64+ty*4+r)*KDEF + h*256 + kt*64 + tx*4+cc] = (ushort)f2bf1(acc[r][cc]);
}

__global__ void wcombB_k(const float* __restrict__ opw, const float* __restrict__ vpb,
                         ushort* __restrict__ Wfull)
{
  const int l = blockIdx.x; const int c = threadIdx.x;
  ushort* wr = Wfull + ((size_t)l*256 + c)*KDEF;
  for (int h=0; h<8; ++h) {
    float s = 0.f;
    for (int j=0;j<32;++j) s += opw[(size_t)l*65536 + (size_t)c*256 + h*32+j] * vpb[l*256 + h*32+j];
    wr[2048 + h] = (ushort)f2bf1(s);
  }
  for (int zz=2056; zz<KDEF; ++zz) wr[zz] = 0;
}

// ---------------------------------------------------------------------------
// Fused cls-LN2 + reg3 + cls3 + ref update + output write.
// ---------------------------------------------------------------------------
__global__ __launch_bounds__(256) void regcls3_k(
    const float* __restrict__ rc2,
    const float* __restrict__ lnw, const float* __restrict__ lnb,
    const float* __restrict__ rw3, const float* __restrict__ rb3,
    const float* __restrict__ cw3, const float* __restrict__ cb3,
    float* __restrict__ ref, float* __restrict__ outL)
{
  __shared__ float Wr[10*272];
  __shared__ float Wc[10*272];
  for (int i=threadIdx.x; i<2560; i+=256) {
    const int o = i>>8, k = i&255;
    const int si = o*272 + (k>>6)*68 + (k&63);
    Wr[si] = rw3[i]; Wc[si] = cw3[i];
  }
  __syncthreads();
  const int t = threadIdx.x;
  const int row = t>>3, g = (t>>2)&1, sl = t&3;
  const int R = blockIdx.x*32 + row;
  const bool act = R < ROWS;
  const float* base = rc2 + (size_t)(act?R:0)*512 + g*256 + sl*64;
  float4 v[16];
  #pragma unroll
  for (int jj=0;jj<16;++jj) v[jj] = *(const float4*)(base + 4*jj);
  float s1 = 0.f, s2 = 0.f;
  #pragma unroll
  for (int jj=0;jj<16;++jj) {
    s1 += v[jj].x+v[jj].y+v[jj].z+v[jj].w;
    s2 += v[jj].x*v[jj].x+v[jj].y*v[jj].y+v[jj].z*v[jj].z+v[jj].w*v[jj].w;
  }
  s1 += __shfl_xor(s1,1); s1 += __shfl_xor(s1,2);
  s2 += __shfl_xor(s2,1); s2 += __shfl_xor(s2,2);
  if (g) {
    const float mean = s1*(1.0f/256.0f);
    const float var = s2*(1.0f/256.0f) - mean*mean;
    const float rs = rsqrtf(var + 1e-5f);
    #pragma unroll
    for (int jj=0;jj<16;++jj) {
      const float4 w4 = *(const float4*)(lnw + sl*64 + 4*jj);
      const float4 b4 = *(const float4*)(lnb + sl*64 + 4*jj);
      v[jj].x = fmaxf((v[jj].x-mean)*rs*w4.x + b4.x, 0.f);
      v[jj].y = fmaxf((v[jj].y-mean)*rs*w4.y + b4.y, 0.f);
      v[jj].z = fmaxf((v[jj].z-mean)*rs*w4.z + b4.z, 0.f);
      v[jj].w = fmaxf((v[jj].w-mean)*rs*w4.w + b4.w, 0.f);
    }
  }
  const float* Wg = g ? Wc : Wr;
  float acc[10] = {};
  #pragma unroll
  for (int jj=0;jj<16;++jj) {
    #pragma unroll
    for (int o=0;o<10;++o) {
      const float4 w = *(const float4*)&Wg[o*272 + sl*68 + 4*jj];
      acc[o] += v[jj].x*w.x + v[jj].y*w.y + v[jj].z*w.z + v[jj].w*w.w;
    }
  }
  #pragma unroll
  for (int o=0;o<10;++o) {
    acc[o] += __shfl_xor(acc[o], 1);
    acc[o] += __shfl_xor(acc[o], 2);
  }
  if (act && sl == 0) {
    if (g) {
      float* oc = outL + (size_t)R*20;
      #pragma unroll
      for (int o=0;o<10;++o) oc[o] = acc[o] + cb3[o];
    } else {
      float tt[10];
      #pragma unroll
      for (int o=0;o<10;++o) tt[o] = acc[o] + rb3[o];
      const float rx = invsigf_(ref[R*3+0]);
      const float ry = invsigf_(ref[R*3+1]);
      const float rz = invsigf_(ref[R*3+2]);
      const float nx = sigmoidf_(tt[0]+rx);
      const float ny = sigmoidf_(tt[1]+ry);
      const float nz = sigmoidf_(tt[4]+rz);
      ref[R*3+0]=nx; ref[R*3+1]=ny; ref[R*3+2]=nz;
      float* o = outL + (size_t)R*20 + 10;
      o[0]=nx*102.4f-51.2f; o[1]=ny*102.4f-51.2f; o[2]=tt[2]; o[3]=tt[3];
      o[4]=nz*8.0f-5.0f; o[5]=tt[5]; o[6]=tt[6]; o[7]=tt[7]; o[8]=tt[8]; o[9]=tt[9];
    }
  }
}

__global__ void init_k(const float* __restrict__ qe, float* __restrict__ qpos,
                       float* __restrict__ q, ushort* __restrict__ qb, ushort* __restrict__ qpb)
{
  const int t = blockIdx.x*blockDim.x + threadIdx.x;
  const int row = t >> 6; const int cc = (t & 63) << 2;
  const int n = row % NQQ;
  const float4 vp = *(const float4*)(qe + (size_t)n*512 + cc);
  const float4 vq = *(const float4*)(qe + (size_t)n*512 + 256 + cc);
  *(float4*)(qpos + (size_t)row*256 + cc) = vp;
  *(float4*)(q    + (size_t)row*256 + cc) = vq;
  *(ushort4*)(qb  + (size_t)row*256 + cc) = pk4(vq);
  float4 s; s.x=vq.x+vp.x; s.y=vq.y+vp.y; s.z=vq.z+vp.z; s.w=vq.w+vp.w;
  *(ushort4*)(qpb + (size_t)row*256 + cc) = pk4(s);
}

__global__ void prep_k(const float* __restrict__ ow, const float* __restrict__ ob,
                       const float* __restrict__ aw, const float* __restrict__ ab,
                       const float* __restrict__ rw, const float* __restrict__ rb,
                       const float* __restrict__ cw, const float* __restrict__ cb,
                       ushort* cwAb, float* cbA, ushort* cwBb, float* cbB)
{
  const int i = blockIdx.x*blockDim.x + threadIdx.x;
  if (i < 6*96*256) {
    const int l = i/(96*256), r = (i/256)%96, k = i%256;
    const float v = (r<64) ? ow[((size_t)l*64 + r)*256 + k] : aw[((size_t)l*32 + (r-64))*256 + k];
    cwAb[i] = (ushort)f2bf1(v);
  }
  if (i < 576) { const int l = i/96, r = i%96; cbA[i] = (r<64) ? ob[l*64+r] : ab[l*32 + r-64]; }
  if (i < 6*512*256) {
    const int l = i/(512*256), r = (i/256)%512, k = i%256;
    const float v = (r<256) ? rw[((size_t)l*256+r)*256+k] : cw[((size_t)l*256 + (r-256))*256 + k];
    cwBb[i] = (ushort)f2bf1(v);
  }
  if (i < 3072) { const int l = i/512, r = i%512; cbB[i] = (r<256) ? rb[l*256+r] : cb[l*256 + r-256]; }
}

__global__ void cvtw_k(const float* __restrict__ s1, const float* __restrict__ s2,
                       const float* __restrict__ s3, const float* __restrict__ s4,
                       const float* __restrict__ s5, const float* __restrict__ s6,
                       const float* __restrict__ s7, ushort* __restrict__ dst)
{
  const int i4 = (blockIdx.x*256 + threadIdx.x)*4;
  if (i4 >= 4325376) return;
  const float* src; int lo;
  if      (i4 < 1179648) { src=s1; lo=i4; }
  else if (i4 < 1572864) { src=s2; lo=i4-1179648; }
  else if (i4 < 1966080) { src=s3; lo=i4-1572864; }
  else if (i4 < 2752512) { src=s4; lo=i4-1966080; }
  else if (i4 < 3538944) { src=s5; lo=i4-2752512; }
  else if (i4 < 3932160) { src=s6; lo=i4-3538944; }
  else                   { src=s7; lo=i4-3932160; }
  const float4 v = *(const float4*)(src+lo);
  *(ushort4*)(dst+i4) = pk4(v);
}

__global__ void cvtbev_k(const float* __restrict__ bev, ushort* __restrict__ bevb)
{
  const size_t i = ((size_t)blockIdx.x*256 + threadIdx.x)*8;
  const float4 a = *(const float4*)(bev+i);
  const float4 b = *(const float4*)(bev+i+4);
  *(ushort4*)(bevb+i)   = pk4(a);
  *(ushort4*)(bevb+i+4) = pk4(b);
}

extern "C" void kernel_launch(void* const* d_in, const int* in_sizes, int n_in,
                              void* d_out, int out_size, void* d_ws, size_t ws_size,
                              hipStream_t stream)
{
  const float* bev      = (const float*)d_in[0];
  const float* qe       = (const float*)d_in[1];
  const float* ref_w    = (const float*)d_in[2];
  const float* ref_b    = (const float*)d_in[3];
  const float* sa_in_w  = (const float*)d_in[4];
  const float* sa_in_b  = (const float*)d_in[5];
  const float* sa_out_w = (const float*)d_in[6];
  const float* sa_out_b = (const float*)d_in[7];
  const float* ln_w     = (const float*)d_in[8];
  const float* ln_b     = (const float*)d_in[9];
  const float* off_w    = (const float*)d_in[10];
  const float* off_b    = (const float*)d_in[11];
  const float* aw_w     = (const float*)d_in[12];
  const float* aw_b     = (const float*)d_in[13];
  const float* vproj_w  = (const float*)d_in[14];
  const float* vproj_b  = (const float*)d_in[15];
  const float* oproj_w  = (const float*)d_in[16];
  const float* oproj_b  = (const float*)d_in[17];
  const float* ffn_w1   = (const float*)d_in[18];
  const float* ffn_b1   = (const float*)d_in[19];
  const float* ffn_w2   = (const float*)d_in[20];
  const float* ffn_b2   = (const float*)d_in[21];
  const float* reg_w1   = (const float*)d_in[22];
  const float* reg_b1   = (const float*)d_in[23];
  const float* reg_w2   = (const float*)d_in[24];
  const float* reg_b2   = (const float*)d_in[25];
  const float* reg_w3   = (const float*)d_in[26];
  const float* reg_b3   = (const float*)d_in[27];
  const float* cls_w1   = (const float*)d_in[28];
  const float* cls_b1   = (const float*)d_in[29];
  const float* cls_w2   = (const float*)d_in[30];
  const float* cls_b2   = (const float*)d_in[31];
  const float* cls_w3   = (const float*)d_in[32];
  const float* cls_b3   = (const float*)d_in[33];
  const float* cls_ln_w = (const float*)d_in[34];
  const float* cls_ln_b = (const float*)d_in[35];
  float* out = (float*)d_out;

  float* ws    = (float*)d_ws;
  float* qpos  = ws;                    // 921600
  float* q     = qpos + 921600;
  float* tA    = q    + 921600;
  float* tB    = tA   + 921600;
  float* rc2   = tB   + 921600;         // 1843200
  float* cls1f = rc2  + 1843200;        // (unused)
  float* offaw = cls1f+ 921600;         // 345600
  float* ref   = offaw+ 345600;         // 10800
  float* cbA   = ref  + 10800;          // 576
  float* cbB   = cbA  + 576;            // 3072
  ushort* usb  = (ushort*)(ws + 6811248);
  ushort* rr   = usb;                   // 7488000 = 3600*2080 (aliases below)
  ushort* QKb  = usb;                   // 1843200
  ushort* Vb   = usb + 1843200;         // 921600
  ushort* tAb  = usb + 2764800;         // 921600
  ushort* W5b  = usb + 3686400;         // 1843200
  ushort* clsb = usb + 5529600;         // 921600
  ushort* regb = usb + 6451200;         // 921600
  ushort* qb   = usb + 7488000;         // 921600
  ushort* qpb  = usb + 8409600;         // 921600
  ushort* bevb = usb + 9331200;         // 40960000
  ushort* wbf  = usb + 50291200;
  ushort* siwb = wbf;                   // 1179648
  ushort* sowb = wbf + 1179648;         // 393216
  ushort* f1wb = wbf + 1966080;         // 786432
  ushort* f2wb = wbf + 2752512;         // 786432
  ushort* r2wb = wbf + 3538944;         // 393216
  ushort* c2wb = wbf + 3932160;         // 393216
  ushort* cwAb = wbf + 4325376;         // 147456
  ushort* cwBb = wbf + 4472832;         // 786432
  ushort* Wfull= wbf + 5259264;         // 3194880 = 6*256*2080

  auto G = [&](int BM, const ushort* A0, const ushort* A1, int NA, int lda,
               const ushort* W0, const ushort* W1, int NW,
               const float* B0, const float* B1, int NB,
               void* Y0, int ldy0, int obf0,
               void* Y1, int ldy1, int obf1, int NY,
               int M, int N, int K, int reluN) {
    dim3 grid((M+BM-1)/BM, (N+63)/64);
    if (BM==64)
      gemmb_k<64><<<grid, 256, 0, stream>>>(A0,A1,NA,lda,W0,W1,NW,B0,B1,NB,
                                            Y0,ldy0,obf0,Y1,ldy1,obf1,NY,M,N,K,reluN);
    else
      gemmb_k<32><<<grid, 256, 0, stream>>>(A0,A1,NA,lda,W0,W1,NW,B0,B1,NB,
                                            Y0,ldy0,obf0,Y1,ldy1,obf1,NY,M,N,K,reluN);
  };

  // one-time converts + prep
  cvtbev_k<<<20000, 256, 0, stream>>>(bev, bevb);
  cvtw_k<<<4224, 256, 0, stream>>>(sa_in_w, sa_out_w, oproj_w, ffn_w1, ffn_w2, reg_w2, cls_w2, wbf);
  prep_k<<<3072, 256, 0, stream>>>(off_w, off_b, aw_w, aw_b, reg_w1, reg_b1, cls_w1, cls_b1,
                                   cwAb, cbA, cwBb, cbB);
  wcomb_k<<<dim3(16,8,6), 256, 0, stream>>>(oproj_w, vproj_w, Wfull);
  wcombB_k<<<6, 256, 0, stream>>>(oproj_w, vproj_b, Wfull);
  init_k<<<900, 256, 0, stream>>>(qe, qpos, q, qb, qpb);
  {
    dim3 grid((ROWS+63)/64, 1);
    gemm_k<<<grid, 256, 0, stream>>>(qpos, 256, ref_w, ref_b, ref, ROWS, 3, 256, 3, 2);
  }

  for (int i=0;i<NLAYER;++i) {
    const float* sib = sa_in_b + (size_t)i*768;
    const ushort* siw = siwb + (size_t)i*196608;
    // ---- self-attention: fused QKV ----
    G(64, qpb, qb, 512, 256, siw, siw, BIGN, sib, sib, BIGN,
      QKb, 512, 1, Vb, 256, 1, 512, ROWS, 768, 256, 0);
    attn3_k<<<dim3(32,15), 256, 0, stream>>>(QKb, Vb, tAb);
    G(32, tAb, tAb, BIGN, 256, sowb + (size_t)i*65536, nullptr, BIGN,
      sa_out_b + (size_t)i*256, nullptr, BIGN,
      tB, 256, 0, nullptr, 0, 0, BIGN, ROWS, 256, 256, 0);
    ln_k<<<900, 256, 0, stream>>>(tB, 256, q, ln_w + (size_t)(i*3+0)*256, ln_b + (size_t)(i*3+0)*256,
                                  q, nullptr, qpos, qpb, 0);
    // ---- deformable cross-attention (gather + fused Wcomb gemm) ----
    G(32, qpb, qpb, BIGN, 256, cwAb + (size_t)i*24576, nullptr, BIGN,
      cbA + i*96, nullptr, BIGN,
      offaw, 96, 0, nullptr, 0, 0, BIGN, ROWS, 96, 256, 0);
    gather_k<<<ROWS, 512, 0, stream>>>(bevb, offaw, ref, rr);
    G(32, rr, rr, BIGN, KDEF, Wfull + (size_t)i*256*KDEF, nullptr, BIGN,
      oproj_b + (size_t)i*256, nullptr, BIGN,
      tA, 256, 0, nullptr, 0, 0, BIGN, ROWS, 256, KDEF, 0);
    ln_k<<<900, 256, 0, stream>>>(tA, 256, q, ln_w + (size_t)(i*3+1)*256, ln_b + (size_t)(i*3+1)*256,
                                  q, qb, nullptr, nullptr, 0);
    // ---- FFN ----
    G(64, qb, qb, BIGN, 256, f1wb + (size_t)i*131072, nullptr, BIGN,
      ffn_b1 + (size_t)i*512, nullptr, BIGN,
      W5b, 512, 1, nullptr, 0, 0, BIGN, ROWS, 512, 256, 512);
    G(32, W5b, W5b, BIGN, 512, f2wb + (size_t)i*131072, nullptr, BIGN,
      ffn_b2 + (size_t)i*256, nullptr, BIGN,
      tA, 256, 0, nullptr, 0, 0, BIGN, ROWS, 256, 512, 0);
    ln_k<<<900, 256, 0, stream>>>(tA, 256, q, ln_w + (size_t)(i*3+2)*256, ln_b + (size_t)(i*3+2)*256,
                                  q, qb, qpos, qpb, 0);
    // ---- reg1|cls1 dual-output ----
    G(64, qb, qb, BIGN, 256, cwBb + (size_t)i*131072, nullptr, BIGN,
      cbB + i*512, nullptr, BIGN,
      regb, 256, 1, cls1f, 256, 0, 256, ROWS, 512, 256, 256);
    ln_k<<<900, 256, 0, stream>>>(cls1f, 256, nullptr,
                                  cls_ln_w + (size_t)(i*2+0)*256, cls_ln_b + (size_t)(i*2+0)*256,
                                  nullptr, clsb, nullptr, nullptr, 1);
    // ---- reg2|cls2 merged ----
    G(64, regb, clsb, 256, 256,
      r2wb + (size_t)i*65536, c2wb + (size_t)i*65536, 256,
      reg_b2 + (size_t)i*256, cls_b2 + (size_t)i*256, 256,
      rc2, 512, 0, nullptr, 0, 0, BIGN, ROWS, 512, 256, 256);
    // ---- fused clsLN2 + reg3 + cls3 + refupdate + output ----
    regcls3_k<<<(ROWS+31)/32, 256, 0, stream>>>(rc2,
        cls_ln_w + (size_t)(i*2+1)*256, cls_ln_b + (size_t)(i*2+1)*256,
        reg_w3 + (size_t)i*2560, reg_b3 + (size_t)i*10,
        cls_w3 + (size_t)i*2560, cls_b3 + (size_t)i*10,
        ref, out + (size_t)i*ROWS*20);
  }
}

// Round 12
// 1167.603 us; speedup vs baseline: 1.1469x; 1.0035x over previous
//
#include <hip/hip_runtime.h>
#include <math.h>

#define DD 256
#define NQQ 900
#define NBS 4
#define NLAYER 6
#define BEVH 200
#define BEVW 200
#define ROWS (NBS*NQQ)   // 3600
#define BIGN (1<<30)
#define KDEF 2080        // deform fused K: 2048 + 8 sacc + 24 zero

typedef __attribute__((ext_vector_type(8))) short bf16x8;
typedef __attribute__((ext_vector_type(4))) float f32x4;

__device__ __forceinline__ float sigmoidf_(float x){ return 1.0f/(1.0f+expf(-x)); }
__device__ __forceinline__ float invsigf_(float x){
  x = fminf(fmaxf(x,0.0f),1.0f);
  float lo = fmaxf(x,1e-5f), hi = fmaxf(1.0f-x,1e-5f);
  return logf(lo/hi);
}
__device__ __forceinline__ unsigned f2bf1(float x){
  unsigned u = __float_as_uint(x);
  return (u + 0x7fffu + ((u>>16)&1u)) >> 16;
}
__device__ __forceinline__ unsigned pk2(float a, float b){
  return f2bf1(a) | (f2bf1(b)<<16);
}
__device__ __forceinline__ float bf2f(unsigned u){ return __uint_as_float(u<<16); }
__device__ __forceinline__ ushort4 pk4(float4 y){
  ushort4 o; o.x=(ushort)f2bf1(y.x); o.y=(ushort)f2bf1(y.y);
  o.z=(ushort)f2bf1(y.z); o.w=(ushort)f2bf1(y.w); return o;
}

// ---------------------------------------------------------------------------
// fp32 GEMM (ref head only).
// ---------------------------------------------------------------------------
__global__ __launch_bounds__(256) void gemm_k(
    const float* __restrict__ A, int lda,
    const float* __restrict__ W, const float* __restrict__ B,
    float* __restrict__ Y, int M, int N, int K, int ldy, int act)
{
  __shared__ float As[2][32][66];
  __shared__ float Ws[2][32][66];
  const int t = threadIdx.x;
  const int m0 = blockIdx.x*64, n0 = blockIdx.y*64;
  const int lr = t >> 2, kq = (t & 3) << 3;
  const int tx = t & 15, ty = t >> 4;
  const bool aok = (m0 + lr) < M;
  const bool wok = (n0 + lr) < N;
  const float* ap  = A + (size_t)(m0+lr)*lda + kq;
  const float* wp  = W + (size_t)(n0+lr)*K + kq;
  float4 pa[2], pw[2];
  auto loadch = [&](int kc) {
    #pragma unroll
    for (int i=0;i<2;++i) {
      pa[i] = aok ? *(const float4*)(ap + kc + i*4) : make_float4(0,0,0,0);
      pw[i] = wok ? *(const float4*)(wp + kc + i*4) : make_float4(0,0,0,0);
    }
  };
  auto storech = [&](int bf) {
    #pragma unroll
    for (int i=0;i<2;++i) {
      const int kk = kq + i*4;
      As[bf][kk+0][lr]=pa[i].x; As[bf][kk+1][lr]=pa[i].y;
      As[bf][kk+2][lr]=pa[i].z; As[bf][kk+3][lr]=pa[i].w;
      Ws[bf][kk+0][lr]=pw[i].x; Ws[bf][kk+1][lr]=pw[i].y;
      Ws[bf][kk+2][lr]=pw[i].z; Ws[bf][kk+3][lr]=pw[i].w;
    }
  };
  float acc[4][4] = {};
  loadch(0); storech(0); __syncthreads();
  const int NC = K >> 5;
  for (int c=0; c<NC; ++c) {
    if (c+1 < NC) loadch((c+1) << 5);
    const int bf = c & 1;
    #pragma unroll
    for (int k=0;k<32;++k) {
      const float4 a4 = *(const float4*)&As[bf][k][ty<<2];
      const float4 w4 = *(const float4*)&Ws[bf][k][tx<<2];
      const float av[4] = {a4.x,a4.y,a4.z,a4.w};
      const float wv[4] = {w4.x,w4.y,w4.z,w4.w};
      #pragma unroll
      for (int r=0;r<4;++r)
        #pragma unroll
        for (int cc=0;cc<4;++cc) acc[r][cc] += av[r]*wv[cc];
    }
    if (c+1 < NC) { storech((c+1)&1); __syncthreads(); }
  }
  const int gn0 = n0 + (tx<<2);
  #pragma unroll
  for (int r=0;r<4;++r) {
    const int gm = m0 + (ty<<2) + r;
    if (gm >= M) continue;
    for (int cc=0; cc<4 && gn0+cc<N; ++cc) {
      float x = acc[r][cc] + (B ? B[gn0+cc] : 0.0f);
      if (act==1) x = fmaxf(x,0.0f);
      else if (act==2) x = sigmoidf_(x);
      Y[(size_t)gm*ldy + gn0+cc] = x;
    }
  }
}

// ---------------------------------------------------------------------------
// bf16 MFMA GEMM v3: templated BM (64 or 32), BN=64. Dual-A/W/bias/Y.
// ---------------------------------------------------------------------------
template<int BM>
__global__ __launch_bounds__(256) void gemmb_k(
    const ushort* __restrict__ A0, const ushort* __restrict__ A1, int NA, int lda,
    const ushort* __restrict__ W0, const ushort* __restrict__ W1, int NW,
    const float* __restrict__ B0, const float* __restrict__ B1, int NB,
    void* __restrict__ Y0, int ldy0, int obf0,
    void* __restrict__ Y1, int ldy1, int obf1, int NY,
    int M, int N, int K, int reluN)
{
  __shared__ ushort As[2][BM*32];
  __shared__ ushort Bs[2][2048];
  const int t = threadIdx.x;
  const int m0 = blockIdx.x*BM, n0 = blockIdx.y*64;
  const ushort* A = (n0 < NA) ? A0 : A1;
  const int srow = t>>2, scb = t&3;
  const int wrow = n0 + srow;
  const bool wok = wrow < N;
  const ushort* wp = (wrow < NW) ? (W0 + (size_t)wrow*K + scb*8)
                                 : (W1 + (size_t)(wrow-NW)*K + scb*8);
  bool aok; const ushort* ap;
  if constexpr (BM==64) { aok = (m0+srow)<M; }
  else { aok = (t<128) && (m0+srow)<M; }
  ap = A + (size_t)(m0 + (aok?srow:0))*lda + scb*8;
  const int sidx = srow*32 + ((scb ^ (srow&3))<<3);
  const bf16x8 zf = {0,0,0,0,0,0,0,0};

  bf16x8 pa, pw;
  auto loadg = [&](int kc){
    pa = aok ? *(const bf16x8*)(ap+kc) : zf;
    pw = wok ? *(const bf16x8*)(wp+kc) : zf;
  };
  auto writes = [&](int bf){
    if (BM==64 || t<128) *(bf16x8*)&As[bf][sidx] = pa;
    *(bf16x8*)&Bs[bf][sidx] = pw;
  };

  const int wv = t>>6, lane = t&63;
  const int fm = lane&15, kb = lane>>4;

  auto writeout = [&](float x, int row, int col){
    if (row >= M || col >= N) return;
    if (col < reluN) x = fmaxf(x, 0.0f);
    if (col < NY) {
      if (obf0) ((ushort*)Y0)[(size_t)row*ldy0 + col] = (ushort)f2bf1(x);
      else      ((float*)Y0)[(size_t)row*ldy0 + col] = x;
    } else {
      const int c2 = col - NY;
      if (obf1) ((ushort*)Y1)[(size_t)row*ldy1 + c2] = (ushort)f2bf1(x);
      else      ((float*)Y1)[(size_t)row*ldy1 + c2] = x;
    }
  };

  const int NS = K>>5;
  if constexpr (BM==64) {
    const int wr = wv>>1, wc = wv&1;
    const int arow0 = wr*32 + fm, arow1 = arow0 + 16;
    const int bcol0 = wc*32 + fm, bcol1 = bcol0 + 16;
    const int ai0 = arow0*32 + ((kb^(arow0&3))<<3);
    const int ai1 = arow1*32 + ((kb^(arow1&3))<<3);
    const int bi0 = bcol0*32 + ((kb^(bcol0&3))<<3);
    const int bi1 = bcol1*32 + ((kb^(bcol1&3))<<3);
    f32x4 acc00={0,0,0,0}, acc01={0,0,0,0}, acc10={0,0,0,0}, acc11={0,0,0,0};
    loadg(0); writes(0); __syncthreads();
    for (int s=0; s<NS; ++s) {
      if (s+1<NS) loadg((s+1)<<5);
      const int bf = s&1;
      bf16x8 a0 = *(bf16x8*)&As[bf][ai0];
      bf16x8 a1 = *(bf16x8*)&As[bf][ai1];
      bf16x8 b0 = *(bf16x8*)&Bs[bf][bi0];
      bf16x8 b1 = *(bf16x8*)&Bs[bf][bi1];
      acc00 = __builtin_amdgcn_mfma_f32_16x16x32_bf16(a0,b0,acc00,0,0,0);
      acc01 = __builtin_amdgcn_mfma_f32_16x16x32_bf16(a0,b1,acc01,0,0,0);
      acc10 = __builtin_amdgcn_mfma_f32_16x16x32_bf16(a1,b0,acc10,0,0,0);
      acc11 = __builtin_amdgcn_mfma_f32_16x16x32_bf16(a1,b1,acc11,0,0,0);
      if (s+1<NS) { __syncthreads(); writes((s+1)&1); __syncthreads(); }
    }
    #pragma unroll
    for (int fr=0; fr<2; ++fr)
      #pragma unroll
      for (int fc=0; fc<2; ++fc) {
        const f32x4 av = fr ? (fc ? acc11 : acc10) : (fc ? acc01 : acc00);
        const int col = n0 + wc*32 + fc*16 + fm;
        const float bias = (col<N) ? ((col<NB) ? B0[col] : B1[col-NB]) : 0.0f;
        #pragma unroll
        for (int r=0; r<4; ++r)
          writeout(av[r] + bias, m0 + wr*32 + fr*16 + kb*4 + r, col);
      }
  } else {
    const int ai0 = fm*32 + ((kb^(fm&3))<<3);
    const int ai1 = (fm+16)*32 + ((kb^(fm&3))<<3);
    const int bcol = wv*16 + fm;
    const int bi = bcol*32 + ((kb^(bcol&3))<<3);
    f32x4 acc0={0,0,0,0}, acc1={0,0,0,0};
    loadg(0); writes(0); __syncthreads();
    for (int s=0; s<NS; ++s) {
      if (s+1<NS) loadg((s+1)<<5);
      const int bf = s&1;
      bf16x8 a0 = *(bf16x8*)&As[bf][ai0];
      bf16x8 a1 = *(bf16x8*)&As[bf][ai1];
      bf16x8 b  = *(bf16x8*)&Bs[bf][bi];
      acc0 = __builtin_amdgcn_mfma_f32_16x16x32_bf16(a0,b,acc0,0,0,0);
      acc1 = __builtin_amdgcn_mfma_f32_16x16x32_bf16(a1,b,acc1,0,0,0);
      if (s+1<NS) { __syncthreads(); writes((s+1)&1); __syncthreads(); }
    }
    const int col = n0 + wv*16 + fm;
    const float bias = (col<N) ? ((col<NB) ? B0[col] : B1[col-NB]) : 0.0f;
    #pragma unroll
    for (int r=0; r<4; ++r) {
      writeout(acc0[r] + bias, m0 + kb*4 + r, col);
      writeout(acc1[r] + bias, m0 + 16 + kb*4 + r, col);
    }
  }
}

// ---------------------------------------------------------------------------
// MFMA bf16 flash attention v2: block-shared LDS K/V staging (4 waves share
// one (b,h)); K row-major pitch 40, V transposed pitch 34; double-buffered.
// ---------------------------------------------------------------------------
__global__ __launch_bounds__(256) void attn3_k(
    const ushort* __restrict__ QKb, const ushort* __restrict__ Vb, ushort* __restrict__ Ob)
{
  const int b = blockIdx.x >> 3, h = blockIdx.x & 7;
  const int wv = threadIdx.x >> 6, lane = threadIdx.x & 63;
  const int t = threadIdx.x;
  const int qt = blockIdx.y*64 + wv*16;
  const int lq = lane & 15, lg = lane >> 4;
  const int q = qt + lq;

  __shared__ ushort Ks[2][32*40];
  __shared__ ushort Vt[2][32*34];

  bf16x8 qf = *(const bf16x8*)(QKb + (size_t)(b*NQQ + min(q, NQQ-1))*512 + h*32 + lg*8);
  f32x4 ot0 = {0.f,0.f,0.f,0.f}, ot1 = {0.f,0.f,0.f,0.f};
  float m = -3e38f, l = 0.0f;

  const ushort* kg = QKb + (size_t)b*NQQ*512 + 256 + h*32;
  const ushort* vg = Vb  + (size_t)b*NQQ*256 + h*32;
  const int srow = t>>3, sc4 = (t&7)*4;

  ushort4 kv, vv;
  auto sload = [&](int k0){
    const int gr = min(k0 + srow, NQQ-1);
    kv = *(const ushort4*)(kg + (size_t)gr*512 + sc4);
    vv = *(const ushort4*)(vg + (size_t)gr*256 + sc4);
  };
  auto swrite = [&](int bf){
    *(ushort4*)&Ks[bf][srow*40 + sc4] = kv;
    Vt[bf][(sc4+0)*34 + srow] = vv.x;
    Vt[bf][(sc4+1)*34 + srow] = vv.y;
    Vt[bf][(sc4+2)*34 + srow] = vv.z;
    Vt[bf][(sc4+3)*34 + srow] = vv.w;
  };

  const int pbase = (lq + ((lg&1)<<5)) << 2;
  const bool hiC = (lg >> 1);
  const int NC = (NQQ + 31) >> 5;   // 29

  sload(0); swrite(0); __syncthreads();
  for (int c = 0; c < NC; ++c) {
    const int k0 = c<<5;
    if (c+1 < NC) sload((c+1)<<5);
    const int bf = c&1;
    bf16x8 kf0 = *(bf16x8*)&Ks[bf][lq*40 + lg*8];
    bf16x8 kf1 = *(bf16x8*)&Ks[bf][(16+lq)*40 + lg*8];
    const f32x4 z = {0.f,0.f,0.f,0.f};
    f32x4 s0 = __builtin_amdgcn_mfma_f32_16x16x32_bf16(kf0, qf, z, 0, 0, 0);
    f32x4 s1 = __builtin_amdgcn_mfma_f32_16x16x32_bf16(kf1, qf, z, 0, 0, 0);
    const float sc = 0.17677669529663687f;
    float p0[4], p1[4];
    #pragma unroll
    for (int r=0;r<4;++r) { p0[r] = s0[r]*sc; p1[r] = s1[r]*sc; }
    if (k0 + 32 > NQQ) {
      #pragma unroll
      for (int r=0;r<4;++r) {
        if (k0 + 4*lg + r      >= NQQ) p0[r] = -3e38f;
        if (k0 + 16 + 4*lg + r >= NQQ) p1[r] = -3e38f;
      }
    }
    float cm = fmaxf(fmaxf(fmaxf(p0[0],p0[1]),fmaxf(p0[2],p0[3])),
                     fmaxf(fmaxf(p1[0],p1[1]),fmaxf(p1[2],p1[3])));
    cm = fmaxf(cm, __shfl_xor(cm, 16));
    cm = fmaxf(cm, __shfl_xor(cm, 32));
    const float mn = fmaxf(m, cm);
    const float corr = __expf(m - mn);
    m = mn;
    float rs = 0.0f;
    #pragma unroll
    for (int r=0;r<4;++r) { p0[r] = __expf(p0[r]-mn); rs += p0[r]; }
    #pragma unroll
    for (int r=0;r<4;++r) { p1[r] = __expf(p1[r]-mn); rs += p1[r]; }
    rs += __shfl_xor(rs, 16);
    rs += __shfl_xor(rs, 32);
    l = l*corr + rs;
    ot0 *= corr; ot1 *= corr;

    const int c00 = (int)pk2(p0[0],p0[1]), c01 = (int)pk2(p0[2],p0[3]);
    const int c10 = (int)pk2(p1[0],p1[1]), c11 = (int)pk2(p1[2],p1[3]);
    const int A0 = __builtin_amdgcn_ds_bpermute(pbase,    c00);
    const int B0 = __builtin_amdgcn_ds_bpermute(pbase,    c10);
    const int A1 = __builtin_amdgcn_ds_bpermute(pbase,    c01);
    const int B1 = __builtin_amdgcn_ds_bpermute(pbase,    c11);
    const int A2 = __builtin_amdgcn_ds_bpermute(pbase+64, c00);
    const int B2 = __builtin_amdgcn_ds_bpermute(pbase+64, c10);
    const int A3 = __builtin_amdgcn_ds_bpermute(pbase+64, c01);
    const int B3 = __builtin_amdgcn_ds_bpermute(pbase+64, c11);
    union { bf16x8 v; int u[4]; } pv;
    pv.u[0] = hiC ? B0 : A0; pv.u[1] = hiC ? B1 : A1;
    pv.u[2] = hiC ? B2 : A2; pv.u[3] = hiC ? B3 : A3;

    bf16x8 vf0, vf1;
    {
      union { bf16x8 v; unsigned u[4]; } u0, u1;
      const int rb = 8*lg;
      #pragma unroll
      for (int jj=0;jj<4;++jj) {
        u0.u[jj] = *(const unsigned*)&Vt[bf][lq*34 + rb + 2*jj];
        u1.u[jj] = *(const unsigned*)&Vt[bf][(16+lq)*34 + rb + 2*jj];
      }
      vf0 = u0.v; vf1 = u1.v;
    }
    ot0 = __builtin_amdgcn_mfma_f32_16x16x32_bf16(vf0, pv.v, ot0, 0, 0, 0);
    ot1 = __builtin_amdgcn_mfma_f32_16x16x32_bf16(vf1, pv.v, ot1, 0, 0, 0);
    if (c+1 < NC) { __syncthreads(); swrite((c+1)&1); __syncthreads(); }
  }
  if (q < NQQ && qt < NQQ) {
    const float inv = 1.0f / l;
    ushort* op = Ob + (size_t)(b*NQQ + q)*256 + h*32;
    uint2 w0, w1;
    w0.x = pk2(ot0[0]*inv, ot0[1]*inv); w0.y = pk2(ot0[2]*inv, ot0[3]*inv);
    w1.x = pk2(ot1[0]*inv, ot1[1]*inv); w1.y = pk2(ot1[2]*inv, ot1[3]*inv);
    *(uint2*)(op + 4*lg)      = w0;
    *(uint2*)(op + 16 + 4*lg) = w1;
  }
}

// ---------------------------------------------------------------------------
// LayerNorm: optional f32 out, bf16 out, bf16(out+qpos) out.
// ---------------------------------------------------------------------------
__global__ __launch_bounds__(256) void ln_k(
    const float* X, int xld, const float* R,
    const float* __restrict__ w, const float* __restrict__ b,
    float* Y, ushort* Yb, const float* qpos, ushort* Ypb, int relu)
{
  const int row = blockIdx.x*4 + (threadIdx.x>>6);
  const int lane = threadIdx.x & 63;
  if (row >= ROWS) return;
  float4 x = *(const float4*)(X + (size_t)row*xld + (lane<<2));
  if (R) { const float4 r = *(const float4*)(R + (size_t)row*256 + (lane<<2)); x.x+=r.x; x.y+=r.y; x.z+=r.z; x.w+=r.w; }
  float s = x.x+x.y+x.z+x.w;
  #pragma unroll
  for (int o=32;o>0;o>>=1) s += __shfl_xor(s,o);
  const float mean = s * (1.0f/256.0f);
  float4 d; d.x=x.x-mean; d.y=x.y-mean; d.z=x.z-mean; d.w=x.w-mean;
  float s2 = d.x*d.x+d.y*d.y+d.z*d.z+d.w*d.w;
  #pragma unroll
  for (int o=32;o>0;o>>=1) s2 += __shfl_xor(s2,o);
  const float rs = rsqrtf(s2*(1.0f/256.0f) + 1e-5f);
  const float4 wv = *(const float4*)(w + (lane<<2));
  const float4 bv = *(const float4*)(b + (lane<<2));
  float4 y;
  y.x = d.x*rs*wv.x + bv.x; y.y = d.y*rs*wv.y + bv.y;
  y.z = d.z*rs*wv.z + bv.z; y.w = d.w*rs*wv.w + bv.w;
  if (relu) { y.x=fmaxf(y.x,0.f); y.y=fmaxf(y.y,0.f); y.z=fmaxf(y.z,0.f); y.w=fmaxf(y.w,0.f); }
  if (Y)  *(float4*)(Y + (size_t)row*256 + (lane<<2)) = y;
  if (Yb) *(ushort4*)(Yb + (size_t)row*256 + (lane<<2)) = pk4(y);
  if (Ypb) {
    const float4 qp = *(const float4*)(qpos + (size_t)row*256 + (lane<<2));
    float4 zz; zz.x=y.x+qp.x; zz.y=y.y+qp.y; zz.z=y.z+qp.z; zz.w=y.w+qp.w;
    *(ushort4*)(Ypb + (size_t)row*256 + (lane<<2)) = pk4(zz);
  }
}

// ---------------------------------------------------------------------------
// Deformable gather -> rr row-major [row][2080] bf16 (2048 feat | 8 sacc | 24 z)
// ---------------------------------------------------------------------------
__global__ __launch_bounds__(512) void gather_k(
    const ushort* __restrict__ bevb, const float* __restrict__ offaw,
    const float* __restrict__ ref, ushort* __restrict__ rr)
{
  const int row = blockIdx.x;
  const int h = threadIdx.x >> 6, lane = threadIdx.x & 63;
  const int b = row / NQQ;
  const float refx = ref[row*3+0], refy = ref[row*3+1];
  const float* oa = offaw + (size_t)row*96;
  float aw[4];
  {
    const float a0=oa[64+h*4+0], a1=oa[64+h*4+1], a2=oa[64+h*4+2], a3=oa[64+h*4+3];
    const float mx = fmaxf(fmaxf(a0,a1), fmaxf(a2,a3));
    const float e0=__expf(a0-mx), e1=__expf(a1-mx), e2=__expf(a2-mx), e3=__expf(a3-mx);
    const float inv = 1.0f/(e0+e1+e2+e3);
    aw[0]=e0*inv; aw[1]=e1*inv; aw[2]=e2*inv; aw[3]=e3*inv;
  }
  float r0=0.f, r1=0.f, r2=0.f, r3=0.f, sacc=0.f;
  const ushort* bb = bevb + (size_t)b*BEVH*BEVW*DD;
  #pragma unroll
  for (int p=0;p<4;++p) {
    const float ox = oa[h*8+p*2+0], oy = oa[h*8+p*2+1];
    const float x = (refx + ox*(1.0f/BEVW))*BEVW - 0.5f;
    const float y = (refy + oy*(1.0f/BEVH))*BEVH - 0.5f;
    const float x0f = floorf(x), y0f = floorf(y);
    const int x0 = (int)x0f, y0 = (int)y0f;
    const float fx = x - x0f, fy = y - y0f;
    #pragma unroll
    for (int dy=0;dy<2;++dy) {
      #pragma unroll
      for (int dx=0;dx<2;++dx) {
        const int xi = x0+dx, yi = y0+dy;
        if (xi < 0 || xi >= BEVW || yi < 0 || yi >= BEVH) continue;
        const float wgt = (dx ? fx : 1.0f-fx) * (dy ? fy : 1.0f-fy) * aw[p];
        const ushort4 g = *(const ushort4*)(bb + (size_t)(yi*BEVW + xi)*DD + (lane<<2));
        r0 += wgt*bf2f(g.x); r1 += wgt*bf2f(g.y);
        r2 += wgt*bf2f(g.z); r3 += wgt*bf2f(g.w);
        sacc += wgt;
      }
    }
  }
  ushort4 o;
  o.x = (ushort)f2bf1(r0); o.y = (ushort)f2bf1(r1);
  o.z = (ushort)f2bf1(r2); o.w = (ushort)f2bf1(r3);
  ushort* rrow = rr + (size_t)row*KDEF;
  *(ushort4*)&rrow[h*256 + (lane<<2)] = o;
  if (lane == 0) rrow[2048 + h] = (ushort)f2bf1(sacc);
  else if (lane < 4) rrow[2048 + lane*8 + h] = 0;
}

// ---------------------------------------------------------------------------
// One-time: Wfull[l][c][2080] = [ oproj@blockdiag(vproj) | Bmat | 0 ] in bf16
// ---------------------------------------------------------------------------
__global__ __launch_bounds__(256) void wcomb_k(
    const float* __restrict__ opw, const float* __restrict__ vpw,
    ushort* __restrict__ Wfull)
{
  const int l = blockIdx.z, h = blockIdx.y;
  const int ct = blockIdx.x & 3, kt = blockIdx.x >> 2;
  __shared__ float Ao[64][33];
  __shared__ float Bo[32][65];
  const int t = threadIdx.x;
  for (int i=t; i<2048; i+=256) {
    const int r = i>>5, j = i&31;
    Ao[r][j] = opw[(size_t)l*65536 + (size_t)(ct*64 + r)*256 + h*32 + j];
  }
  for (int i=t; i<2048; i+=256) {
    const int j = i>>6, kk = i&63;
    Bo[j][kk] = vpw[(size_t)l*65536 + (size_t)(h*32 + j)*256 + kt*64 + kk];
  }
  __syncthreads();
  const int tx = t&15, ty = t>>4;
  float acc[4][4] = {};
  for (int j=0;j<32;++j) {
    float a[4], bv[4];
    #pragma unroll
    for (int r=0;r<4;++r) a[r] = Ao[ty*4+r][j];
    #pragma unroll
    for (int cc=0;cc<4;++cc) bv[cc] = Bo[j][tx*4+cc];
    #pragma unroll
    for (int r=0;r<4;++r)
      #pragma unroll
      for (int cc=0;cc<4;++cc) acc[r][cc] += a[r]*bv[cc];
  }
  #pragma unroll
  for (int r=0;r<4;++r)
    #pragma unroll
    for (int cc=0;cc<4;++cc)
      Wfull[((size_t)l*256 + ct*64+ty*4+r)*KDEF + h*256 + kt*64 + tx*4+cc] = (ushort)f2bf1(acc[r][cc]);
}

__global__ void wcombB_k(const float* __restrict__ opw, const float* __restrict__ vpb,
                         ushort* __restrict__ Wfull)
{
  const int l = blockIdx.x; const int c = threadIdx.x;
  ushort* wr = Wfull + ((size_t)l*256 + c)*KDEF;
  for (int h=0; h<8; ++h) {
    float s = 0.f;
    for (int j=0;j<32;++j) s += opw[(size_t)l*65536 + (size_t)c*256 + h*32+j] * vpb[l*256 + h*32+j];
    wr[2048 + h] = (ushort)f2bf1(s);
  }
  for (int zz=2056; zz<KDEF; ++zz) wr[zz] = 0;
}

// ---------------------------------------------------------------------------
// Fused cls-LN2 + reg3 + cls3 + ref update + output write.
// ---------------------------------------------------------------------------
__global__ __launch_bounds__(256) void regcls3_k(
    const float* __restrict__ rc2,
    const float* __restrict__ lnw, const float* __restrict__ lnb,
    const float* __restrict__ rw3, const float* __restrict__ rb3,
    const float* __restrict__ cw3, const float* __restrict__ cb3,
    float* __restrict__ ref, float* __restrict__ outL)
{
  __shared__ float Wr[10*272];
  __shared__ float Wc[10*272];
  for (int i=threadIdx.x; i<2560; i+=256) {
    const int o = i>>8, k = i&255;
    const int si = o*272 + (k>>6)*68 + (k&63);
    Wr[si] = rw3[i]; Wc[si] = cw3[i];
  }
  __syncthreads();
  const int t = threadIdx.x;
  const int row = t>>3, g = (t>>2)&1, sl = t&3;
  const int R = blockIdx.x*32 + row;
  const bool act = R < ROWS;
  const float* base = rc2 + (size_t)(act?R:0)*512 + g*256 + sl*64;
  float4 v[16];
  #pragma unroll
  for (int jj=0;jj<16;++jj) v[jj] = *(const float4*)(base + 4*jj);
  float s1 = 0.f, s2 = 0.f;
  #pragma unroll
  for (int jj=0;jj<16;++jj) {
    s1 += v[jj].x+v[jj].y+v[jj].z+v[jj].w;
    s2 += v[jj].x*v[jj].x+v[jj].y*v[jj].y+v[jj].z*v[jj].z+v[jj].w*v[jj].w;
  }
  s1 += __shfl_xor(s1,1); s1 += __shfl_xor(s1,2);
  s2 += __shfl_xor(s2,1); s2 += __shfl_xor(s2,2);
  if (g) {
    const float mean = s1*(1.0f/256.0f);
    const float var = s2*(1.0f/256.0f) - mean*mean;
    const float rs = rsqrtf(var + 1e-5f);
    #pragma unroll
    for (int jj=0;jj<16;++jj) {
      const float4 w4 = *(const float4*)(lnw + sl*64 + 4*jj);
      const float4 b4 = *(const float4*)(lnb + sl*64 + 4*jj);
      v[jj].x = fmaxf((v[jj].x-mean)*rs*w4.x + b4.x, 0.f);
      v[jj].y = fmaxf((v[jj].y-mean)*rs*w4.y + b4.y, 0.f);
      v[jj].z = fmaxf((v[jj].z-mean)*rs*w4.z + b4.z, 0.f);
      v[jj].w = fmaxf((v[jj].w-mean)*rs*w4.w + b4.w, 0.f);
    }
  }
  const float* Wg = g ? Wc : Wr;
  float acc[10] = {};
  #pragma unroll
  for (int jj=0;jj<16;++jj) {
    #pragma unroll
    for (int o=0;o<10;++o) {
      const float4 w = *(const float4*)&Wg[o*272 + sl*68 + 4*jj];
      acc[o] += v[jj].x*w.x + v[jj].y*w.y + v[jj].z*w.z + v[jj].w*w.w;
    }
  }
  #pragma unroll
  for (int o=0;o<10;++o) {
    acc[o] += __shfl_xor(acc[o], 1);
    acc[o] += __shfl_xor(acc[o], 2);
  }
  if (act && sl == 0) {
    if (g) {
      float* oc = outL + (size_t)R*20;
      #pragma unroll
      for (int o=0;o<10;++o) oc[o] = acc[o] + cb3[o];
    } else {
      float tt[10];
      #pragma unroll
      for (int o=0;o<10;++o) tt[o] = acc[o] + rb3[o];
      const float rx = invsigf_(ref[R*3+0]);
      const float ry = invsigf_(ref[R*3+1]);
      const float rz = invsigf_(ref[R*3+2]);
      const float nx = sigmoidf_(tt[0]+rx);
      const float ny = sigmoidf_(tt[1]+ry);
      const float nz = sigmoidf_(tt[4]+rz);
      ref[R*3+0]=nx; ref[R*3+1]=ny; ref[R*3+2]=nz;
      float* o = outL + (size_t)R*20 + 10;
      o[0]=nx*102.4f-51.2f; o[1]=ny*102.4f-51.2f; o[2]=tt[2]; o[3]=tt[3];
      o[4]=nz*8.0f-5.0f; o[5]=tt[5]; o[6]=tt[6]; o[7]=tt[7]; o[8]=tt[8]; o[9]=tt[9];
    }
  }
}

__global__ void init_k(const float* __restrict__ qe, float* __restrict__ qpos,
                       float* __restrict__ q, ushort* __restrict__ qb, ushort* __restrict__ qpb)
{
  const int t = blockIdx.x*blockDim.x + threadIdx.x;
  const int row = t >> 6; const int cc = (t & 63) << 2;
  const int n = row % NQQ;
  const float4 vp = *(const float4*)(qe + (size_t)n*512 + cc);
  const float4 vq = *(const float4*)(qe + (size_t)n*512 + 256 + cc);
  *(float4*)(qpos + (size_t)row*256 + cc) = vp;
  *(float4*)(q    + (size_t)row*256 + cc) = vq;
  *(ushort4*)(qb  + (size_t)row*256 + cc) = pk4(vq);
  float4 s; s.x=vq.x+vp.x; s.y=vq.y+vp.y; s.z=vq.z+vp.z; s.w=vq.w+vp.w;
  *(ushort4*)(qpb + (size_t)row*256 + cc) = pk4(s);
}

__global__ void prep_k(const float* __restrict__ ow, const float* __restrict__ ob,
                       const float* __restrict__ aw, const float* __restrict__ ab,
                       const float* __restrict__ rw, const float* __restrict__ rb,
                       const float* __restrict__ cw, const float* __restrict__ cb,
                       ushort* cwAb, float* cbA, ushort* cwBb, float* cbB)
{
  const int i = blockIdx.x*blockDim.x + threadIdx.x;
  if (i < 6*96*256) {
    const int l = i/(96*256), r = (i/256)%96, k = i%256;
    const float v = (r<64) ? ow[((size_t)l*64 + r)*256 + k] : aw[((size_t)l*32 + (r-64))*256 + k];
    cwAb[i] = (ushort)f2bf1(v);
  }
  if (i < 576) { const int l = i/96, r = i%96; cbA[i] = (r<64) ? ob[l*64+r] : ab[l*32 + r-64]; }
  if (i < 6*512*256) {
    const int l = i/(512*256), r = (i/256)%512, k = i%256;
    const float v = (r<256) ? rw[((size_t)l*256+r)*256+k] : cw[((size_t)l*256 + (r-256))*256 + k];
    cwBb[i] = (ushort)f2bf1(v);
  }
  if (i < 3072) { const int l = i/512, r = i%512; cbB[i] = (r<256) ? rb[l*256+r] : cb[l*256 + r-256]; }
}

__global__ void cvtw_k(const float* __restrict__ s1, const float* __restrict__ s2,
                       const float* __restrict__ s3, const float* __restrict__ s4,
                       const float* __restrict__ s5, const float* __restrict__ s6,
                       const float* __restrict__ s7, ushort* __restrict__ dst)
{
  const int i4 = (blockIdx.x*256 + threadIdx.x)*4;
  if (i4 >= 4325376) return;
  const float* src; int lo;
  if      (i4 < 1179648) { src=s1; lo=i4; }
  else if (i4 < 1572864) { src=s2; lo=i4-1179648; }
  else if (i4 < 1966080) { src=s3; lo=i4-1572864; }
  else if (i4 < 2752512) { src=s4; lo=i4-1966080; }
  else if (i4 < 3538944) { src=s5; lo=i4-2752512; }
  else if (i4 < 3932160) { src=s6; lo=i4-3538944; }
  else                   { src=s7; lo=i4-3932160; }
  const float4 v = *(const float4*)(src+lo);
  *(ushort4*)(dst+i4) = pk4(v);
}

__global__ void cvtbev_k(const float* __restrict__ bev, ushort* __restrict__ bevb)
{
  const size_t i = ((size_t)blockIdx.x*256 + threadIdx.x)*8;
  const float4 a = *(const float4*)(bev+i);
  const float4 b = *(const float4*)(bev+i+4);
  *(ushort4*)(bevb+i)   = pk4(a);
  *(ushort4*)(bevb+i+4) = pk4(b);
}

extern "C" void kernel_launch(void* const* d_in, const int* in_sizes, int n_in,
                              void* d_out, int out_size, void* d_ws, size_t ws_size,
                              hipStream_t stream)
{
  const float* bev      = (const float*)d_in[0];
  const float* qe       = (const float*)d_in[1];
  const float* ref_w    = (const float*)d_in[2];
  const float* ref_b    = (const float*)d_in[3];
  const float* sa_in_w  = (const float*)d_in[4];
  const float* sa_in_b  = (const float*)d_in[5];
  const float* sa_out_w = (const float*)d_in[6];
  const float* sa_out_b = (const float*)d_in[7];
  const float* ln_w     = (const float*)d_in[8];
  const float* ln_b     = (const float*)d_in[9];
  const float* off_w    = (const float*)d_in[10];
  const float* off_b    = (const float*)d_in[11];
  const float* aw_w     = (const float*)d_in[12];
  const float* aw_b     = (const float*)d_in[13];
  const float* vproj_w  = (const float*)d_in[14];
  const float* vproj_b  = (const float*)d_in[15];
  const float* oproj_w  = (const float*)d_in[16];
  const float* oproj_b  = (const float*)d_in[17];
  const float* ffn_w1   = (const float*)d_in[18];
  const float* ffn_b1   = (const float*)d_in[19];
  const float* ffn_w2   = (const float*)d_in[20];
  const float* ffn_b2   = (const float*)d_in[21];
  const float* reg_w1   = (const float*)d_in[22];
  const float* reg_b1   = (const float*)d_in[23];
  const float* reg_w2   = (const float*)d_in[24];
  const float* reg_b2   = (const float*)d_in[25];
  const float* reg_w3   = (const float*)d_in[26];
  const float* reg_b3   = (const float*)d_in[27];
  const float* cls_w1   = (const float*)d_in[28];
  const float* cls_b1   = (const float*)d_in[29];
  const float* cls_w2   = (const float*)d_in[30];
  const float* cls_b2   = (const float*)d_in[31];
  const float* cls_w3   = (const float*)d_in[32];
  const float* cls_b3   = (const float*)d_in[33];
  const float* cls_ln_w = (const float*)d_in[34];
  const float* cls_ln_b = (const float*)d_in[35];
  float* out = (float*)d_out;

  float* ws    = (float*)d_ws;
  float* qpos  = ws;                    // 921600
  float* q     = qpos + 921600;
  float* tA    = q    + 921600;
  float* tB    = tA   + 921600;
  float* rc2   = tB   + 921600;         // 1843200
  float* cls1f = rc2  + 1843200;        // 921600
  float* offaw = cls1f+ 921600;         // 345600
  float* ref   = offaw+ 345600;         // 10800
  float* cbA   = ref  + 10800;          // 576
  float* cbB   = cbA  + 576;            // 3072
  ushort* usb  = (ushort*)(ws + 6811248);
  ushort* rr   = usb;                   // 7488000 = 3600*2080 (aliases below)
  ushort* QKb  = usb;                   // 1843200
  ushort* Vb   = usb + 1843200;         // 921600
  ushort* tAb  = usb + 2764800;         // 921600
  ushort* W5b  = usb + 3686400;         // 1843200
  ushort* clsb = usb + 5529600;         // 921600
  ushort* regb = usb + 6451200;         // 921600
  ushort* qb   = usb + 7488000;         // 921600
  ushort* qpb  = usb + 8409600;         // 921600
  ushort* bevb = usb + 9331200;         // 40960000
  ushort* wbf  = usb + 50291200;
  ushort* siwb = wbf;                   // 1179648
  ushort* sowb = wbf + 1179648;         // 393216
  ushort* f1wb = wbf + 1966080;         // 786432
  ushort* f2wb = wbf + 2752512;         // 786432
  ushort* r2wb = wbf + 3538944;         // 393216
  ushort* c2wb = wbf + 3932160;         // 393216
  ushort* cwAb = wbf + 4325376;         // 147456
  ushort* cwBb = wbf + 4472832;         // 786432
  ushort* Wfull= wbf + 5259264;         // 3194880 = 6*256*2080

  auto G = [&](int BM, const ushort* A0, const ushort* A1, int NA, int lda,
               const ushort* W0, const ushort* W1, int NW,
               const float* B0, const float* B1, int NB,
               void* Y0, int ldy0, int obf0,
               void* Y1, int ldy1, int obf1, int NY,
               int M, int N, int K, int reluN) {
    dim3 grid((M+BM-1)/BM, (N+63)/64);
    if (BM==64)
      gemmb_k<64><<<grid, 256, 0, stream>>>(A0,A1,NA,lda,W0,W1,NW,B0,B1,NB,
                                            Y0,ldy0,obf0,Y1,ldy1,obf1,NY,M,N,K,reluN);
    else
      gemmb_k<32><<<grid, 256, 0, stream>>>(A0,A1,NA,lda,W0,W1,NW,B0,B1,NB,
                                            Y0,ldy0,obf0,Y1,ldy1,obf1,NY,M,N,K,reluN);
  };

  // one-time converts + prep
  cvtbev_k<<<20000, 256, 0, stream>>>(bev, bevb);
  cvtw_k<<<4224, 256, 0, stream>>>(sa_in_w, sa_out_w, oproj_w, ffn_w1, ffn_w2, reg_w2, cls_w2, wbf);
  prep_k<<<3072, 256, 0, stream>>>(off_w, off_b, aw_w, aw_b, reg_w1, reg_b1, cls_w1, cls_b1,
                                   cwAb, cbA, cwBb, cbB);
  wcomb_k<<<dim3(16,8,6), 256, 0, stream>>>(oproj_w, vproj_w, Wfull);
  wcombB_k<<<6, 256, 0, stream>>>(oproj_w, vproj_b, Wfull);
  init_k<<<900, 256, 0, stream>>>(qe, qpos, q, qb, qpb);
  {
    dim3 grid((ROWS+63)/64, 1);
    gemm_k<<<grid, 256, 0, stream>>>(qpos, 256, ref_w, ref_b, ref, ROWS, 3, 256, 3, 2);
  }

  for (int i=0;i<NLAYER;++i) {
    const float* sib = sa_in_b + (size_t)i*768;
    const ushort* siw = siwb + (size_t)i*196608;
    // ---- self-attention: fused QKV (BM=32 for occupancy) ----
    G(32, qpb, qb, 512, 256, siw, siw, BIGN, sib, sib, BIGN,
      QKb, 512, 1, Vb, 256, 1, 512, ROWS, 768, 256, 0);
    attn3_k<<<dim3(32,15), 256, 0, stream>>>(QKb, Vb, tAb);
    G(32, tAb, tAb, BIGN, 256, sowb + (size_t)i*65536, nullptr, BIGN,
      sa_out_b + (size_t)i*256, nullptr, BIGN,
      tB, 256, 0, nullptr, 0, 0, BIGN, ROWS, 256, 256, 0);
    ln_k<<<900, 256, 0, stream>>>(tB, 256, q, ln_w + (size_t)(i*3+0)*256, ln_b + (size_t)(i*3+0)*256,
                                  q, nullptr, qpos, qpb, 0);
    // ---- deformable cross-attention (gather + fused Wcomb gemm) ----
    G(32, qpb, qpb, BIGN, 256, cwAb + (size_t)i*24576, nullptr, BIGN,
      cbA + i*96, nullptr, BIGN,
      offaw, 96, 0, nullptr, 0, 0, BIGN, ROWS, 96, 256, 0);
    gather_k<<<ROWS, 512, 0, stream>>>(bevb, offaw, ref, rr);
    G(32, rr, rr, BIGN, KDEF, Wfull + (size_t)i*256*KDEF, nullptr, BIGN,
      oproj_b + (size_t)i*256, nullptr, BIGN,
      tA, 256, 0, nullptr, 0, 0, BIGN, ROWS, 256, KDEF, 0);
    ln_k<<<900, 256, 0, stream>>>(tA, 256, q, ln_w + (size_t)(i*3+1)*256, ln_b + (size_t)(i*3+1)*256,
                                  q, qb, nullptr, nullptr, 0);
    // ---- FFN (BM=32) ----
    G(32, qb, qb, BIGN, 256, f1wb + (size_t)i*131072, nullptr, BIGN,
      ffn_b1 + (size_t)i*512, nullptr, BIGN,
      W5b, 512, 1, nullptr, 0, 0, BIGN, ROWS, 512, 256, 512);
    G(32, W5b, W5b, BIGN, 512, f2wb + (size_t)i*131072, nullptr, BIGN,
      ffn_b2 + (size_t)i*256, nullptr, BIGN,
      tA, 256, 0, nullptr, 0, 0, BIGN, ROWS, 256, 512, 0);
    ln_k<<<900, 256, 0, stream>>>(tA, 256, q, ln_w + (size_t)(i*3+2)*256, ln_b + (size_t)(i*3+2)*256,
                                  q, qb, qpos, qpb, 0);
    // ---- reg1|cls1 dual-output (BM=32) ----
    G(32, qb, qb, BIGN, 256, cwBb + (size_t)i*131072, nullptr, BIGN,
      cbB + i*512, nullptr, BIGN,
      regb, 256, 1, cls1f, 256, 0, 256, ROWS, 512, 256, 256);
    ln_k<<<900, 256, 0, stream>>>(cls1f, 256, nullptr,
                                  cls_ln_w + (size_t)(i*2+0)*256, cls_ln_b + (size_t)(i*2+0)*256,
                                  nullptr, clsb, nullptr, nullptr, 1);
    // ---- reg2|cls2 merged (BM=32) ----
    G(32, regb, clsb, 256, 256,
      r2wb + (size_t)i*65536, c2wb + (size_t)i*65536, 256,
      reg_b2 + (size_t)i*256, cls_b2 + (size_t)i*256, 256,
      rc2, 512, 0, nullptr, 0, 0, BIGN, ROWS, 512, 256, 256);
    // ---- fused clsLN2 + reg3 + cls3 + refupdate + output ----
    regcls3_k<<<(ROWS+31)/32, 256, 0, stream>>>(rc2,
        cls_ln_w + (size_t)(i*2+1)*256, cls_ln_b + (size_t)(i*2+1)*256,
        reg_w3 + (size_t)i*2560, reg_b3 + (size_t)i*10,
        cls_w3 + (size_t)i*2560, cls_b3 + (size_t)i*10,
        ref, out + (size_t)i*ROWS*20);
  }
}